// Round 2
// baseline (11074.870 us; speedup 1.0000x reference)
//
#include <hip/hip_runtime.h>
#include <hip/hip_bf16.h>

#define TPB 256

typedef __hip_bfloat16 bf16;

__device__ inline float ldv(const float* p) { return *p; }
__device__ inline float ldv(const bf16* p)  { return __bfloat162float(*p); }
__device__ inline void  stv(float* p, float v) { *p = v; }
__device__ inline void  stv(bf16* p, float v)  { *p = __float2bfloat16(v); }

// ---------------------------------------------------------------------------
// Block-level {sum, sumsq} reduction + atomic into stats[2*co], stats[2*co+1].
// All threads of the block must call this (inactive lanes pass 0).
// ---------------------------------------------------------------------------
__device__ inline void block_stats(float s, float s2, float* stats, int co)
{
    for (int off = 32; off > 0; off >>= 1) {
        s  += __shfl_down(s, off, 64);
        s2 += __shfl_down(s2, off, 64);
    }
    __shared__ float sm[TPB / 64], sm2[TPB / 64];
    const int lane = threadIdx.x & 63, wid = threadIdx.x >> 6;
    if (lane == 0) { sm[wid] = s; sm2[wid] = s2; }
    __syncthreads();
    if (threadIdx.x == 0) {
        float a = 0.f, b = 0.f;
        for (int i = 0; i < TPB / 64; ++i) { a += sm[i]; b += sm2[i]; }
        atomicAdd(&stats[2 * co],     a);
        atomicAdd(&stats[2 * co + 1], b);
    }
}

// ---------------------------------------------------------------------------
// Direct 3x3x3 conv, padding 1, stride 1 or 2. grid: (ceil(spatial/TPB), OC).
// Fused per-channel sum/sumsq if stats != nullptr.
// ---------------------------------------------------------------------------
template <typename Tin, typename Tout>
__global__ __launch_bounds__(TPB) void conv3d_k(
    const Tin* __restrict__ in, const float* __restrict__ w,
    Tout* __restrict__ out, float* __restrict__ stats, int IC,
    int ID, int IH, int IW,
    int OD, int OH, int OW, int stride)
{
    __shared__ float sw[64 * 27];
    const int co = blockIdx.y;
    const int nw = IC * 27;
    for (int i = threadIdx.x; i < nw; i += TPB) sw[i] = w[(long)co * nw + i];
    __syncthreads();

    const long spatial_out = (long)OD * OH * OW;
    const long sp = (long)blockIdx.x * TPB + threadIdx.x;
    const bool valid = sp < spatial_out;

    float acc = 0.f;
    if (valid) {
        const int x = (int)(sp % OW);
        const long t = sp / OW;
        const int y = (int)(t % OH);
        const int z = (int)(t / OH);
        const long chs = (long)ID * IH * IW;
        for (int kz = 0; kz < 3; ++kz) {
            const int iz = z * stride - 1 + kz;
            if ((unsigned)iz >= (unsigned)ID) continue;
            for (int ky = 0; ky < 3; ++ky) {
                const int iy = y * stride - 1 + ky;
                if ((unsigned)iy >= (unsigned)IH) continue;
                for (int kx = 0; kx < 3; ++kx) {
                    const int ix = x * stride - 1 + kx;
                    if ((unsigned)ix >= (unsigned)IW) continue;
                    const Tin* ip = in + ((long)iz * IH + iy) * IW + ix;
                    const float* wp = sw + (kz * 9 + ky * 3 + kx);
                    for (int ci = 0; ci < IC; ++ci)
                        acc += ldv(ip + (long)ci * chs) * wp[ci * 27];
                }
            }
        }
        stv(out + (long)co * spatial_out + sp, acc);
    }
    if (stats)
        block_stats(valid ? acc : 0.f, valid ? acc * acc : 0.f, stats, co);
}

// ---------------------------------------------------------------------------
// Transposed conv, stride 2, kernel 3 (lhs-dilated, pad (1,2)). out = 2x in.
// o even -> tap k=1, i=o/2 ; o odd -> k=0, i=(o-1)/2 and k=2, i=(o+1)/2 if <ID
// ---------------------------------------------------------------------------
__global__ __launch_bounds__(TPB) void tconv3d_k(
    const bf16* __restrict__ in, const float* __restrict__ w,
    bf16* __restrict__ out, float* __restrict__ stats, int IC,
    int ID, int IH, int IW)
{
    __shared__ float sw[64 * 27];
    const int co = blockIdx.y;
    const int nw = IC * 27;
    for (int i = threadIdx.x; i < nw; i += TPB) sw[i] = w[(long)co * nw + i];
    __syncthreads();

    const int OD = ID * 2, OH = IH * 2, OW = IW * 2;
    const long spatial_out = (long)OD * OH * OW;
    const long sp = (long)blockIdx.x * TPB + threadIdx.x;
    const bool valid = sp < spatial_out;

    float acc = 0.f;
    if (valid) {
        const int x = (int)(sp % OW);
        const long t = sp / OW;
        const int y = (int)(t % OH);
        const int z = (int)(t / OH);

        int kzs[2], izs[2], nz = 0;
        int kys[2], iys[2], ny = 0;
        int kxs[2], ixs[2], nx = 0;
        if (z & 1) { izs[0] = (z - 1) >> 1; kzs[0] = 0; nz = 1;
                     int i2 = (z + 1) >> 1; if (i2 < ID) { izs[1] = i2; kzs[1] = 2; nz = 2; } }
        else       { izs[0] = z >> 1; kzs[0] = 1; nz = 1; }
        if (y & 1) { iys[0] = (y - 1) >> 1; kys[0] = 0; ny = 1;
                     int i2 = (y + 1) >> 1; if (i2 < IH) { iys[1] = i2; kys[1] = 2; ny = 2; } }
        else       { iys[0] = y >> 1; kys[0] = 1; ny = 1; }
        if (x & 1) { ixs[0] = (x - 1) >> 1; kxs[0] = 0; nx = 1;
                     int i2 = (x + 1) >> 1; if (i2 < IW) { ixs[1] = i2; kxs[1] = 2; nx = 2; } }
        else       { ixs[0] = x >> 1; kxs[0] = 1; nx = 1; }

        const long chs = (long)ID * IH * IW;
        for (int a = 0; a < nz; ++a)
            for (int b = 0; b < ny; ++b)
                for (int c = 0; c < nx; ++c) {
                    const bf16* ip = in + ((long)izs[a] * IH + iys[b]) * IW + ixs[c];
                    const float* wp = sw + (kzs[a] * 9 + kys[b] * 3 + kxs[c]);
                    for (int ci = 0; ci < IC; ++ci)
                        acc += ldv(ip + (long)ci * chs) * wp[ci * 27];
                }
        stv(out + (long)co * spatial_out + sp, acc);
    }
    if (stats)
        block_stats(valid ? acc : 0.f, valid ? acc * acc : 0.f, stats, co);
}

// ---------------------------------------------------------------------------
// In-place BN + ReLU on bf16 buffer. grid: (nblk, C).
// ---------------------------------------------------------------------------
__global__ __launch_bounds__(TPB) void bnrelu_k(
    bf16* __restrict__ buf, const float* __restrict__ stats,
    const float* __restrict__ g, const float* __restrict__ b,
    long spatial, float invN)
{
    const int c = blockIdx.y;
    const float mean = stats[2 * c] * invN;
    const float var  = stats[2 * c + 1] * invN - mean * mean;
    const float sc = rsqrtf(var + 1e-5f) * g[c];
    const float sh = b[c] - mean * sc;
    bf16* p = buf + (long)c * spatial;
    for (long i = (long)blockIdx.x * TPB + threadIdx.x; i < spatial;
         i += (long)gridDim.x * TPB) {
        float v = __bfloat162float(p[i]) * sc + sh;
        p[i] = __float2bfloat16(v > 0.f ? v : 0.f);
    }
}

static inline int nblocks(long n) { return (int)((n + TPB - 1) / TPB); }
static inline int imin(int a, int b) { return a < b ? a : b; }

extern "C" void kernel_launch(void* const* d_in, const int* in_sizes, int n_in,
                              void* d_out, int out_size, void* d_ws, size_t ws_size,
                              hipStream_t stream)
{
    const float* x    = (const float*)d_in[0];
    const float* w0   = (const float*)d_in[1];
    const float* g0   = (const float*)d_in[2];
    const float* b0   = (const float*)d_in[3];
    const float* w1   = (const float*)d_in[4];
    const float* g1   = (const float*)d_in[5];
    const float* b1   = (const float*)d_in[6];
    const float* w2   = (const float*)d_in[7];
    const float* g2   = (const float*)d_in[8];
    const float* b2   = (const float*)d_in[9];
    const float* w3   = (const float*)d_in[10];
    const float* g3   = (const float*)d_in[11];
    const float* b3   = (const float*)d_in[12];
    const float* wt3  = (const float*)d_in[13];
    const float* gt3  = (const float*)d_in[14];
    const float* bt3  = (const float*)d_in[15];
    const float* wt2  = (const float*)d_in[16];
    const float* gt2  = (const float*)d_in[17];
    const float* bt2  = (const float*)d_in[18];
    const float* wt1  = (const float*)d_in[19];
    const float* gt1  = (const float*)d_in[20];
    const float* bt1  = (const float*)d_in[21];
    const float* wout = (const float*)d_in[22];

    const long S128 = 128L * 128 * 128;
    const long S64  = 64L * 64 * 64;
    const long S32  = 32L * 32 * 32;
    const long S16  = 16L * 16 * 16;

    // Workspace layout (stats fp32 first, then bf16 activations; ~164 MB total)
    float* stats = (float*)d_ws;              // 512 floats
    bf16* base = (bf16*)((char*)d_ws + 2048);
    bf16* cat1 = base;                        // [32][128^3]: tconv1 out ch0-23, s1 ch24-31
    bf16* cat2 = cat1 + 32 * S128;            // [48][64^3] : tconv2 out ch0-31, s2 ch32-47
    bf16* cat3 = cat2 + 48 * S64;             // [64][32^3] : tconv3 out ch0-31, s4 ch32-63
    bf16* s8   = cat3 + 64 * S32;             // [64][16^3]
    bf16* s1 = cat1 + 24 * S128;
    bf16* s2 = cat2 + 32 * S64;
    bf16* s4 = cat3 + 32 * S32;

    hipMemsetAsync(stats, 0, 512 * sizeof(float), stream);

    const int ELT_CAP = 4096;

    // ---- encoder ----
    conv3d_k<float, bf16><<<dim3(nblocks(S128), 8), TPB, 0, stream>>>(
        x, w0, s1, stats + 0, 8, 128, 128, 128, 128, 128, 128, 1);
    bnrelu_k<<<dim3(imin(nblocks(S128), ELT_CAP), 8), TPB, 0, stream>>>(
        s1, stats + 0, g0, b0, S128, 1.f / S128);

    conv3d_k<bf16, bf16><<<dim3(nblocks(S64), 16), TPB, 0, stream>>>(
        s1, w1, s2, stats + 16, 8, 128, 128, 128, 64, 64, 64, 2);
    bnrelu_k<<<dim3(imin(nblocks(S64), ELT_CAP), 16), TPB, 0, stream>>>(
        s2, stats + 16, g1, b1, S64, 1.f / S64);

    conv3d_k<bf16, bf16><<<dim3(nblocks(S32), 32), TPB, 0, stream>>>(
        s2, w2, s4, stats + 48, 16, 64, 64, 64, 32, 32, 32, 2);
    bnrelu_k<<<dim3(imin(nblocks(S32), ELT_CAP), 32), TPB, 0, stream>>>(
        s4, stats + 48, g2, b2, S32, 1.f / S32);

    conv3d_k<bf16, bf16><<<dim3(nblocks(S16), 64), TPB, 0, stream>>>(
        s4, w3, s8, stats + 112, 32, 32, 32, 32, 16, 16, 16, 2);
    bnrelu_k<<<dim3(imin(nblocks(S16), ELT_CAP), 64), TPB, 0, stream>>>(
        s8, stats + 112, g3, b3, S16, 1.f / S16);

    // ---- decoder ----
    tconv3d_k<<<dim3(nblocks(S32), 32), TPB, 0, stream>>>(
        s8, wt3, cat3, stats + 240, 64, 16, 16, 16);
    bnrelu_k<<<dim3(imin(nblocks(S32), ELT_CAP), 32), TPB, 0, stream>>>(
        cat3, stats + 240, gt3, bt3, S32, 1.f / S32);

    tconv3d_k<<<dim3(nblocks(S64), 32), TPB, 0, stream>>>(
        cat3, wt2, cat2, stats + 304, 64, 32, 32, 32);
    bnrelu_k<<<dim3(imin(nblocks(S64), ELT_CAP), 32), TPB, 0, stream>>>(
        cat2, stats + 304, gt2, bt2, S64, 1.f / S64);

    tconv3d_k<<<dim3(nblocks(S128), 24), TPB, 0, stream>>>(
        cat2, wt1, cat1, stats + 368, 48, 64, 64, 64);
    bnrelu_k<<<dim3(imin(nblocks(S128), ELT_CAP), 24), TPB, 0, stream>>>(
        cat1, stats + 368, gt1, bt1, S128, 1.f / S128);

    // out conv: cat1(32,128^3) -> d_out(2,128^3) fp32, no BN
    conv3d_k<bf16, float><<<dim3(nblocks(S128), 2), TPB, 0, stream>>>(
        cat1, wout, (float*)d_out, nullptr, 32, 128, 128, 128, 128, 128, 128, 1);
}

// Round 4
// 5050.901 us; speedup vs baseline: 2.1927x; 2.1927x over previous
//
#include <hip/hip_runtime.h>
#include <hip/hip_bf16.h>

typedef __hip_bfloat16 bf16;
#define TPB 256

// ---- bf16x8 vector helpers (16B) ----
__device__ inline void ld8(const bf16* p, float* v) {
    uint4 u = *(const uint4*)p;
    const unsigned short* s = (const unsigned short*)&u;
#pragma unroll
    for (int j = 0; j < 8; ++j) v[j] = __uint_as_float((unsigned)s[j] << 16);
}
__device__ inline void zero8(float* v) {
#pragma unroll
    for (int j = 0; j < 8; ++j) v[j] = 0.f;
}
__device__ inline void st8(bf16* p, const float* v) {
    bf16 t[8];
#pragma unroll
    for (int j = 0; j < 8; ++j) t[j] = __float2bfloat16(v[j]);
    *(uint4*)p = *(const uint4*)t;
}

// ---------------------------------------------------------------------------
// Weight repack: w [OC][IC][27] -> wr [27][IC][OC]  (fp32)
// ---------------------------------------------------------------------------
__global__ __launch_bounds__(TPB) void repack_w_k(
    const float* __restrict__ w, float* __restrict__ wr, int OC, int IC)
{
    int idx = blockIdx.x * TPB + threadIdx.x;
    int n = OC * IC * 27;
    if (idx >= n) return;
    int co = idx / (IC * 27);
    int ci = (idx / 27) % IC;
    int t  = idx % 27;
    wr[(t * IC + ci) * OC + co] = w[idx];
}

// ---------------------------------------------------------------------------
// conv0: fp32 NCDHW input [8][128^3] -> bf16 channels-last rows (CS, preoff).
// ---------------------------------------------------------------------------
template <int VX>
__global__ __launch_bounds__(TPB) void conv0_k(
    const float* __restrict__ x, const float* __restrict__ wr,
    bf16* __restrict__ out, int CSout)
{
    __shared__ float sw[27 * 8 * 8];
    for (int i = threadIdx.x; i < 27 * 8 * 8; i += TPB) sw[i] = wr[i];
    __syncthreads();

    const int D = 128;
    const long S = (long)D * D * D;
    long v[VX]; int xx[VX], yy[VX], zz[VX]; bool ok[VX];
    const long vb = (long)blockIdx.x * (TPB * VX) + threadIdx.x;
#pragma unroll
    for (int q = 0; q < VX; ++q) {
        v[q] = vb + (long)q * TPB;
        ok[q] = v[q] < S;
        long vv = ok[q] ? v[q] : 0;
        xx[q] = (int)(vv % D); yy[q] = (int)((vv / D) % D); zz[q] = (int)(vv / ((long)D * D));
    }
    float acc[VX][8];
#pragma unroll
    for (int q = 0; q < VX; ++q) zero8(acc[q]);

#pragma unroll 1
    for (int t = 0; t < 27; ++t) {
        const int kz = t / 9, ky = (t / 3) % 3, kx = t % 3;
        const float* swt = sw + t * 64;
        long bi[VX]; bool val[VX];
#pragma unroll
        for (int q = 0; q < VX; ++q) {
            int iz = zz[q] - 1 + kz, iy = yy[q] - 1 + ky, ix = xx[q] - 1 + kx;
            val[q] = ok[q] && (unsigned)iz < (unsigned)D && (unsigned)iy < (unsigned)D
                     && (unsigned)ix < (unsigned)D;
            bi[q] = ((long)iz * D + iy) * D + ix;
        }
        float a[VX][8];
#pragma unroll
        for (int ci = 0; ci < 8; ++ci)
#pragma unroll
            for (int q = 0; q < VX; ++q)
                a[q][ci] = val[q] ? x[ci * S + bi[q]] : 0.f;
#pragma unroll
        for (int j = 0; j < 8; ++j)
#pragma unroll
            for (int c4 = 0; c4 < 8; c4 += 4) {
                float4 wv = *(const float4*)&swt[j * 8 + c4];
#pragma unroll
                for (int q = 0; q < VX; ++q) {
                    acc[q][c4 + 0] += a[q][j] * wv.x;
                    acc[q][c4 + 1] += a[q][j] * wv.y;
                    acc[q][c4 + 2] += a[q][j] * wv.z;
                    acc[q][c4 + 3] += a[q][j] * wv.w;
                }
            }
    }
#pragma unroll
    for (int q = 0; q < VX; ++q)
        if (ok[q]) st8(out + v[q] * CSout, acc[q]);
}

// ---------------------------------------------------------------------------
// Generic channels-last conv, kernel 3, pad 1, stride STRIDE.
// in: bf16 rows of CSin (pre-offset), wr: [27][IC][OC] fp32.
// CFOUT=false: bf16 rows CSout (pre-offset), channel cog0+c.
// CFOUT=true : fp32 channel-first outf[co][spatial].
// grid: (spatial/(TPB*VX), OC/OCT)
// ---------------------------------------------------------------------------
template <int IC, int OCT, int VX, int STRIDE, bool CFOUT>
__global__ __launch_bounds__(TPB) void conv_cl_k(
    const bf16* __restrict__ in, const float* __restrict__ wr,
    bf16* __restrict__ out, float* __restrict__ outf,
    int ID, int IH, int IW, int OD, int OH, int OW,
    int CSin, int CSout, int OC)
{
    __shared__ float sw[27 * IC * OCT];
    const int cog0 = blockIdx.y * OCT;
    for (int i = threadIdx.x; i < 27 * IC * OCT; i += TPB) {
        int t_ci = i / OCT, c = i % OCT;
        sw[i] = wr[t_ci * OC + cog0 + c];
    }
    __syncthreads();

    const long S = (long)OD * OH * OW;
    long v[VX]; int xx[VX], yy[VX], zz[VX]; bool ok[VX];
    const long vb = (long)blockIdx.x * (TPB * VX) + threadIdx.x;
#pragma unroll
    for (int q = 0; q < VX; ++q) {
        v[q] = vb + (long)q * TPB;
        ok[q] = v[q] < S;
        long vv = ok[q] ? v[q] : 0;
        xx[q] = (int)(vv % OW); yy[q] = (int)((vv / OW) % OH);
        zz[q] = (int)(vv / ((long)OW * OH));
    }
    float acc[VX][OCT];
#pragma unroll
    for (int q = 0; q < VX; ++q)
#pragma unroll
        for (int c = 0; c < OCT; ++c) acc[q][c] = 0.f;

#pragma unroll 1
    for (int t = 0; t < 27; ++t) {
        const int kz = t / 9, ky = (t / 3) % 3, kx = t % 3;
        const float* swt = sw + t * IC * OCT;
        long bi[VX]; bool val[VX];
#pragma unroll
        for (int q = 0; q < VX; ++q) {
            int iz = zz[q] * STRIDE - 1 + kz;
            int iy = yy[q] * STRIDE - 1 + ky;
            int ix = xx[q] * STRIDE - 1 + kx;
            val[q] = ok[q] && (unsigned)iz < (unsigned)ID && (unsigned)iy < (unsigned)IH
                     && (unsigned)ix < (unsigned)IW;
            bi[q] = (((long)iz * IH + iy) * IW + ix) * CSin;
        }
#pragma unroll 1
        for (int c8 = 0; c8 < IC; c8 += 8) {
            float a[VX][8];
#pragma unroll
            for (int q = 0; q < VX; ++q) {
                if (val[q]) ld8(in + bi[q] + c8, a[q]); else zero8(a[q]);
            }
#pragma unroll
            for (int j = 0; j < 8; ++j) {
                if constexpr (OCT % 4 == 0) {
#pragma unroll
                    for (int c4 = 0; c4 < OCT; c4 += 4) {
                        float4 wv = *(const float4*)&swt[(c8 + j) * OCT + c4];
#pragma unroll
                        for (int q = 0; q < VX; ++q) {
                            acc[q][c4 + 0] += a[q][j] * wv.x;
                            acc[q][c4 + 1] += a[q][j] * wv.y;
                            acc[q][c4 + 2] += a[q][j] * wv.z;
                            acc[q][c4 + 3] += a[q][j] * wv.w;
                        }
                    }
                } else {
                    float2 wv = *(const float2*)&swt[(c8 + j) * OCT];
#pragma unroll
                    for (int q = 0; q < VX; ++q) {
                        acc[q][0] += a[q][j] * wv.x;
                        acc[q][1] += a[q][j] * wv.y;
                    }
                }
            }
        }
    }
#pragma unroll
    for (int q = 0; q < VX; ++q) {
        if (!ok[q]) continue;
        if constexpr (CFOUT) {
#pragma unroll
            for (int c = 0; c < OCT; ++c)
                outf[(long)(cog0 + c) * S + v[q]] = acc[q][c];
        } else {
            bf16* op = out + v[q] * CSout + cog0;
#pragma unroll
            for (int c8 = 0; c8 < OCT; c8 += 8) st8(op + c8, &acc[q][c8]);
        }
    }
}

// ---------------------------------------------------------------------------
// Transposed conv stride 2 k=3, channels-last, parity-class decomposition.
// grid: (sub_spatial/(TPB*VX), OC/OCT, 8 classes). out dims = 2x in dims.
// ---------------------------------------------------------------------------
template <int IC, int OCT, int VX>
__global__ __launch_bounds__(TPB) void tconv_cl_k(
    const bf16* __restrict__ in, const float* __restrict__ wr,
    bf16* __restrict__ out,
    int ID, int IH, int IW, int CSin, int CSout, int OC)
{
    const int cls = blockIdx.z;
    const int pz = (cls >> 2) & 1, py = (cls >> 1) & 1, px = cls & 1;
    const int nz = 1 + pz, ny = 1 + py, nx = 1 + px;
    const int ntap = nz * ny * nx;

    __shared__ float sw[8 * IC * OCT];
    const int cog0 = blockIdx.y * OCT;
    for (int i = threadIdx.x; i < ntap * IC * OCT; i += TPB) {
        int s = i / (IC * OCT);
        int rem = i % (IC * OCT);
        int ci = rem / OCT, c = rem % OCT;
        int a = s / (ny * nx), b = (s / nx) % ny, cc = s % nx;
        int kz = pz ? (a ? 2 : 0) : 1;
        int ky = py ? (b ? 2 : 0) : 1;
        int kx = px ? (cc ? 2 : 0) : 1;
        sw[i] = wr[((kz * 9 + ky * 3 + kx) * IC + ci) * OC + cog0 + c];
    }
    __syncthreads();

    const int OH = 2 * IH, OW = 2 * IW;
    const long SUB = (long)ID * IH * IW;
    long vi[VX]; int xi[VX], yi[VX], zi[VX]; bool ok[VX];
    const long vb = (long)blockIdx.x * (TPB * VX) + threadIdx.x;
#pragma unroll
    for (int q = 0; q < VX; ++q) {
        vi[q] = vb + (long)q * TPB;
        ok[q] = vi[q] < SUB;
        long vv = ok[q] ? vi[q] : 0;
        xi[q] = (int)(vv % IW); yi[q] = (int)((vv / IW) % IH);
        zi[q] = (int)(vv / ((long)IW * IH));
    }
    float acc[VX][OCT];
#pragma unroll
    for (int q = 0; q < VX; ++q)
#pragma unroll
        for (int c = 0; c < OCT; ++c) acc[q][c] = 0.f;

#pragma unroll 1
    for (int s = 0; s < ntap; ++s) {
        int a = s / (ny * nx), b = (s / nx) % ny, cc = s % nx;
        int dz = pz ? a : 0, dy = py ? b : 0, dx = px ? cc : 0;
        const float* swt = sw + s * IC * OCT;
        long bi[VX]; bool val[VX];
#pragma unroll
        for (int q = 0; q < VX; ++q) {
            int iz = zi[q] + dz, iy = yi[q] + dy, ix = xi[q] + dx;
            val[q] = ok[q] && iz < ID && iy < IH && ix < IW;
            bi[q] = (((long)iz * IH + iy) * IW + ix) * CSin;
        }
#pragma unroll 1
        for (int c8 = 0; c8 < IC; c8 += 8) {
            float a8[VX][8];
#pragma unroll
            for (int q = 0; q < VX; ++q) {
                if (val[q]) ld8(in + bi[q] + c8, a8[q]); else zero8(a8[q]);
            }
#pragma unroll
            for (int j = 0; j < 8; ++j)
#pragma unroll
                for (int c4 = 0; c4 < OCT; c4 += 4) {
                    float4 wv = *(const float4*)&swt[(c8 + j) * OCT + c4];
#pragma unroll
                    for (int q = 0; q < VX; ++q) {
                        acc[q][c4 + 0] += a8[q][j] * wv.x;
                        acc[q][c4 + 1] += a8[q][j] * wv.y;
                        acc[q][c4 + 2] += a8[q][j] * wv.z;
                        acc[q][c4 + 3] += a8[q][j] * wv.w;
                    }
                }
        }
    }
#pragma unroll
    for (int q = 0; q < VX; ++q) {
        if (!ok[q]) continue;
        int z = 2 * zi[q] + pz, y = 2 * yi[q] + py, x = 2 * xi[q] + px;
        long vout = ((long)z * OH + y) * OW + x;
        bf16* op = out + vout * CSout + cog0;
#pragma unroll
        for (int c8 = 0; c8 < OCT; c8 += 8) st8(op + c8, &acc[q][c8]);
    }
}

// ---------------------------------------------------------------------------
// Per-channel-group {sum,sumsq} over channels-last buffer. CG=8.
// grid: (nblk, C/8). buf pre-offset; stats pre-offset (2 floats/channel).
// ---------------------------------------------------------------------------
__global__ __launch_bounds__(TPB) void reduce_cl_k(
    const bf16* __restrict__ buf, long spatial, int CS, float* __restrict__ stats)
{
    const int g0 = blockIdx.y * 8;
    float s[8], s2[8];
#pragma unroll
    for (int c = 0; c < 8; ++c) { s[c] = 0.f; s2[c] = 0.f; }
    for (long v = (long)blockIdx.x * TPB + threadIdx.x; v < spatial;
         v += (long)gridDim.x * TPB) {
        float a[8];
        ld8(buf + v * CS + g0, a);
#pragma unroll
        for (int c = 0; c < 8; ++c) { s[c] += a[c]; s2[c] += a[c] * a[c]; }
    }
#pragma unroll
    for (int c = 0; c < 8; ++c)
        for (int off = 32; off > 0; off >>= 1) {
            s[c]  += __shfl_down(s[c], off, 64);
            s2[c] += __shfl_down(s2[c], off, 64);
        }
    if ((threadIdx.x & 63) == 0) {
#pragma unroll
        for (int c = 0; c < 8; ++c) {
            atomicAdd(&stats[2 * (g0 + c)],     s[c]);
            atomicAdd(&stats[2 * (g0 + c) + 1], s2[c]);
        }
    }
}

// ---------------------------------------------------------------------------
// In-place BN+ReLU on channels-last bf16. CG=8. grid: (nblk, C/8).
// ---------------------------------------------------------------------------
__global__ __launch_bounds__(TPB) void bnrelu_cl_k(
    bf16* __restrict__ buf, long spatial, int CS,
    const float* __restrict__ stats, const float* __restrict__ g,
    const float* __restrict__ b, float invN)
{
    const int g0 = blockIdx.y * 8;
    float sc[8], sh[8];
#pragma unroll
    for (int c = 0; c < 8; ++c) {
        float mean = stats[2 * (g0 + c)] * invN;
        float var  = stats[2 * (g0 + c) + 1] * invN - mean * mean;
        sc[c] = rsqrtf(var + 1e-5f) * g[g0 + c];
        sh[c] = b[g0 + c] - mean * sc[c];
    }
    for (long v = (long)blockIdx.x * TPB + threadIdx.x; v < spatial;
         v += (long)gridDim.x * TPB) {
        bf16* p = buf + v * CS + g0;
        float a[8];
        ld8(p, a);
#pragma unroll
        for (int c = 0; c < 8; ++c) {
            float t = a[c] * sc[c] + sh[c];
            a[c] = t > 0.f ? t : 0.f;
        }
        st8(p, a);
    }
}

static inline int nblocks(long n, int per) { return (int)((n + per - 1) / per); }

extern "C" void kernel_launch(void* const* d_in, const int* in_sizes, int n_in,
                              void* d_out, int out_size, void* d_ws, size_t ws_size,
                              hipStream_t stream)
{
    const float* x    = (const float*)d_in[0];
    const float* w0   = (const float*)d_in[1];
    const float* g0   = (const float*)d_in[2];
    const float* b0   = (const float*)d_in[3];
    const float* w1   = (const float*)d_in[4];
    const float* g1   = (const float*)d_in[5];
    const float* b1   = (const float*)d_in[6];
    const float* w2   = (const float*)d_in[7];
    const float* g2   = (const float*)d_in[8];
    const float* b2   = (const float*)d_in[9];
    const float* w3   = (const float*)d_in[10];
    const float* g3   = (const float*)d_in[11];
    const float* b3   = (const float*)d_in[12];
    const float* wt3  = (const float*)d_in[13];
    const float* gt3  = (const float*)d_in[14];
    const float* bt3  = (const float*)d_in[15];
    const float* wt2  = (const float*)d_in[16];
    const float* gt2  = (const float*)d_in[17];
    const float* bt2  = (const float*)d_in[18];
    const float* wt1  = (const float*)d_in[19];
    const float* gt1  = (const float*)d_in[20];
    const float* bt1  = (const float*)d_in[21];
    const float* wout = (const float*)d_in[22];

    const long S128 = 128L * 128 * 128;
    const long S64  = 64L * 64 * 64;
    const long S32  = 32L * 32 * 32;
    const long S16  = 16L * 16 * 16;

    // ---- workspace ----
    // stats: FLOAT offsets, 2 floats/channel, cumulative channel layout:
    //   conv0 @0 (8ch) | conv1 @16 (16) | conv2 @48 (32) | conv3 @112 (64)
    //   tconv3 @240 (32) | tconv2 @304 (32) | tconv1 @368 (24) -> ends 416 < 512
    float* stats = (float*)d_ws;             // 512 floats
    float* wro   = stats + 512;              // 1728 floats (out-conv weights)
    bf16* base = (bf16*)((char*)d_ws + (512 + 1728) * 4);
    bf16* cat1 = base;                 // [128^3][32]: ch0-23 tconv1, ch24-31 s1
    bf16* cat2 = cat1 + S128 * 32;     // [64^3][48] : ch0-31 tconv2, ch32-47 s2
    bf16* cat3 = cat2 + S64 * 48;      // [32^3][64] : ch0-31 tconv3, ch32-63 s4
    bf16* s8   = cat3 + S32 * 64;      // [16^3][64]
    bf16* s1 = cat1 + 24;              // channel offset within cat1 rows
    bf16* s2 = cat2 + 32;
    bf16* s4 = cat3 + 32;

    // repacked weights live in d_out (consumed before conv_out overwrites it)
    float* wrd  = (float*)d_out;
    float* wr0  = wrd;            // 1728
    float* wr1  = wrd + 1728;     // 3456
    float* wr2  = wrd + 5184;     // 13824
    float* wr3  = wrd + 19008;    // 55296
    float* wrt3 = wrd + 74304;    // 55296
    float* wrt2 = wrd + 129600;   // 55296
    float* wrt1 = wrd + 184896;   // 31104 (end 216000 floats = 864 KB)

    repack_w_k<<<nblocks(1728, TPB),  TPB, 0, stream>>>(w0,  wr0,  8, 8);
    repack_w_k<<<nblocks(3456, TPB),  TPB, 0, stream>>>(w1,  wr1,  16, 8);
    repack_w_k<<<nblocks(13824, TPB), TPB, 0, stream>>>(w2,  wr2,  32, 16);
    repack_w_k<<<nblocks(55296, TPB), TPB, 0, stream>>>(w3,  wr3,  64, 32);
    repack_w_k<<<nblocks(55296, TPB), TPB, 0, stream>>>(wt3, wrt3, 32, 64);
    repack_w_k<<<nblocks(55296, TPB), TPB, 0, stream>>>(wt2, wrt2, 32, 64);
    repack_w_k<<<nblocks(31104, TPB), TPB, 0, stream>>>(wt1, wrt1, 24, 48);
    repack_w_k<<<nblocks(1728, TPB),  TPB, 0, stream>>>(wout, wro, 2, 32);

    hipMemsetAsync(stats, 0, 512 * sizeof(float), stream);

    // ---- encoder ----
    // conv0: x fp32 [8][128^3] -> s1 (cat1 ch24-31)
    conv0_k<4><<<nblocks(S128, TPB * 4), TPB, 0, stream>>>(x, wr0, s1, 32);
    reduce_cl_k<<<dim3(512, 1), TPB, 0, stream>>>(s1, S128, 32, stats + 0);
    bnrelu_cl_k<<<dim3(1024, 1), TPB, 0, stream>>>(s1, S128, 32, stats + 0, g0, b0, 1.f / S128);

    // conv1: s1 (IC=8) -> s2 (cat2 ch32-47, OC=16), stride2 128->64
    conv_cl_k<8, 16, 2, 2, false><<<dim3(nblocks(S64, TPB * 2), 1), TPB, 0, stream>>>(
        s1, wr1, s2, nullptr, 128, 128, 128, 64, 64, 64, 32, 48, 16);
    reduce_cl_k<<<dim3(256, 2), TPB, 0, stream>>>(s2, S64, 48, stats + 16);
    bnrelu_cl_k<<<dim3(256, 2), TPB, 0, stream>>>(s2, S64, 48, stats + 16, g1, b1, 1.f / S64);

    // conv2: s2 (IC=16) -> s4 (cat3 ch32-63, OC=32), stride2 64->32
    conv_cl_k<16, 16, 2, 2, false><<<dim3(nblocks(S32, TPB * 2), 2), TPB, 0, stream>>>(
        s2, wr2, s4, nullptr, 64, 64, 64, 32, 32, 32, 48, 64, 32);
    reduce_cl_k<<<dim3(64, 4), TPB, 0, stream>>>(s4, S32, 64, stats + 48);
    bnrelu_cl_k<<<dim3(64, 4), TPB, 0, stream>>>(s4, S32, 64, stats + 48, g2, b2, 1.f / S32);

    // conv3: s4 (IC=32) -> s8 (OC=64), stride2 32->16
    conv_cl_k<32, 8, 1, 2, false><<<dim3(nblocks(S16, TPB), 8), TPB, 0, stream>>>(
        s4, wr3, s8, nullptr, 32, 32, 32, 16, 16, 16, 64, 64, 64);
    reduce_cl_k<<<dim3(16, 8), TPB, 0, stream>>>(s8, S16, 64, stats + 112);
    bnrelu_cl_k<<<dim3(16, 8), TPB, 0, stream>>>(s8, S16, 64, stats + 112, g3, b3, 1.f / S16);

    // ---- decoder ----
    // tconv3: s8 (IC=64) -> cat3 ch0-31 (OC=32), 16->32
    tconv_cl_k<64, 16, 1><<<dim3(nblocks(S16, TPB), 2, 8), TPB, 0, stream>>>(
        s8, wrt3, cat3, 16, 16, 16, 64, 64, 32);
    reduce_cl_k<<<dim3(64, 4), TPB, 0, stream>>>(cat3, S32, 64, stats + 240);
    bnrelu_cl_k<<<dim3(64, 4), TPB, 0, stream>>>(cat3, S32, 64, stats + 240, gt3, bt3, 1.f / S32);

    // tconv2: cat3 (IC=64) -> cat2 ch0-31 (OC=32), 32->64
    tconv_cl_k<64, 16, 1><<<dim3(nblocks(S32, TPB), 2, 8), TPB, 0, stream>>>(
        cat3, wrt2, cat2, 32, 32, 32, 64, 48, 32);
    reduce_cl_k<<<dim3(256, 4), TPB, 0, stream>>>(cat2, S64, 48, stats + 304);
    bnrelu_cl_k<<<dim3(256, 4), TPB, 0, stream>>>(cat2, S64, 48, stats + 304, gt2, bt2, 1.f / S64);

    // tconv1: cat2 (IC=48) -> cat1 ch0-23 (OC=24), 64->128
    tconv_cl_k<48, 24, 2><<<dim3(nblocks(S64, TPB * 2), 1, 8), TPB, 0, stream>>>(
        cat2, wrt1, cat1, 64, 64, 64, 48, 32, 24);
    reduce_cl_k<<<dim3(512, 3), TPB, 0, stream>>>(cat1, S128, 32, stats + 368);
    bnrelu_cl_k<<<dim3(512, 3), TPB, 0, stream>>>(cat1, S128, 32, stats + 368, gt1, bt1, 1.f / S128);

    // out conv: cat1 (IC=32) -> d_out fp32 [2][128^3]
    conv_cl_k<32, 2, 4, 1, true><<<dim3(nblocks(S128, TPB * 4), 1), TPB, 0, stream>>>(
        cat1, wro, nullptr, (float*)d_out, 128, 128, 128, 128, 128, 128, 32, 0, 2);
}

// Round 5
// 3404.887 us; speedup vs baseline: 3.2526x; 1.4834x over previous
//
#include <hip/hip_runtime.h>
#include <hip/hip_bf16.h>

typedef __hip_bfloat16 bf16;
#define TPB 256

// ---- bf16x8 vector helpers (16B) ----
__device__ inline void ld8(const bf16* p, float* v) {
    uint4 u = *(const uint4*)p;
    const unsigned short* s = (const unsigned short*)&u;
#pragma unroll
    for (int j = 0; j < 8; ++j) v[j] = __uint_as_float((unsigned)s[j] << 16);
}
__device__ inline void zero8(float* v) {
#pragma unroll
    for (int j = 0; j < 8; ++j) v[j] = 0.f;
}
__device__ inline void st8(bf16* p, const float* v) {
    bf16 t[8];
#pragma unroll
    for (int j = 0; j < 8; ++j) t[j] = __float2bfloat16(v[j]);
    *(uint4*)p = *(const uint4*)t;
}

// ---------------------------------------------------------------------------
// Weight repack: w [OC][IC][27] -> wr [27][IC][OC]  (fp32)
// ---------------------------------------------------------------------------
__global__ __launch_bounds__(TPB) void repack_w_k(
    const float* __restrict__ w, float* __restrict__ wr, int OC, int IC)
{
    int idx = blockIdx.x * TPB + threadIdx.x;
    int n = OC * IC * 27;
    if (idx >= n) return;
    int co = idx / (IC * 27);
    int ci = (idx / 27) % IC;
    int t  = idx % 27;
    wr[(t * IC + ci) * OC + co] = w[idx];
}

// ---------------------------------------------------------------------------
// conv0 tiled: fp32 NCDHW input [8][128^3], stride 1, staged into LDS tile
// (channels-last, pitch 8). Output bf16 CL rows (pre-offset). grid: 3D tiles.
// ---------------------------------------------------------------------------
template <int TZ, int TY, int TX>
__global__ __launch_bounds__(TPB) void conv0_tile_k(
    const float* __restrict__ x, const float* __restrict__ wr,
    bf16* __restrict__ out, int CSout)
{
    const int D = 128;
    const long S = (long)D * D * D;
    constexpr int EZ = TZ + 2, EY = TY + 2, EX = TX + 2;
    constexpr int NR = EZ * EY * EX;
    __shared__ __align__(16) bf16 si[NR * 8];
    __shared__ float sw[27 * 64];
    const int ntx = D / TX, nty = D / TY;
    const int bx = blockIdx.x % ntx;
    const int by = (blockIdx.x / ntx) % nty;
    const int bz = blockIdx.x / (ntx * nty);
    const int x0 = bx * TX - 1, y0 = by * TY - 1, z0 = bz * TZ - 1;
    for (int i = threadIdx.x; i < 27 * 64; i += TPB) sw[i] = wr[i];
    for (int i = threadIdx.x; i < NR * 8; i += TPB) {
        int c = i / NR, r = i % NR;
        int rx = r % EX, ry = (r / EX) % EY, rz = r / (EX * EY);
        int gz = z0 + rz, gy = y0 + ry, gx = x0 + rx;
        float v = 0.f;
        if ((unsigned)gz < (unsigned)D && (unsigned)gy < (unsigned)D &&
            (unsigned)gx < (unsigned)D)
            v = x[(long)c * S + ((long)gz * D + gy) * D + gx];
        si[r * 8 + c] = __float2bfloat16(v);
    }
    __syncthreads();
    constexpr int VX = (TZ * TY * TX) / TPB;
    float acc[VX][8];
#pragma unroll
    for (int q = 0; q < VX; ++q) zero8(acc[q]);
    int lx[VX], ly[VX], lz[VX];
#pragma unroll
    for (int q = 0; q < VX; ++q) {
        int l = threadIdx.x + q * TPB;
        lx[q] = l % TX; ly[q] = (l / TX) % TY; lz[q] = l / (TX * TY);
    }
#pragma unroll 1
    for (int t = 0; t < 27; ++t) {
        const int kz = t / 9, ky = (t / 3) % 3, kx = t % 3;
        const float* swt = sw + t * 64;
        float a[VX][8];
#pragma unroll
        for (int q = 0; q < VX; ++q) {
            int r = ((lz[q] + kz) * EY + (ly[q] + ky)) * EX + (lx[q] + kx);
            ld8(si + r * 8, a[q]);
        }
#pragma unroll
        for (int j = 0; j < 8; ++j)
#pragma unroll
            for (int c4 = 0; c4 < 8; c4 += 4) {
                float4 wv = *(const float4*)&swt[j * 8 + c4];
#pragma unroll
                for (int q = 0; q < VX; ++q) {
                    acc[q][c4 + 0] += a[q][j] * wv.x;
                    acc[q][c4 + 1] += a[q][j] * wv.y;
                    acc[q][c4 + 2] += a[q][j] * wv.z;
                    acc[q][c4 + 3] += a[q][j] * wv.w;
                }
            }
    }
#pragma unroll
    for (int q = 0; q < VX; ++q) {
        long vox = ((long)(bz * TZ + lz[q]) * D + (by * TY + ly[q])) * D
                   + (bx * TX + lx[q]);
        st8(out + vox * CSout, acc[q]);
    }
}

// ---------------------------------------------------------------------------
// Tiled channels-last conv, k=3, pad 1, stride S. Input staged in LDS
// (pitch-padded rows). CFOUT=true -> fp32 channel-first output.
// grid.x = (OD/TZ)*(OH/TY)*(OW/TX)
// ---------------------------------------------------------------------------
template <int IC, int OC, int S, int TZ, int TY, int TX, bool CFOUT>
__global__ __launch_bounds__(TPB) void conv_tile_k(
    const bf16* __restrict__ in, const float* __restrict__ wr,
    bf16* __restrict__ out, float* __restrict__ outf,
    int ID, int IH, int IW, int OD, int OH, int OW, int CSin, int CSout)
{
    constexpr int EZ = S * TZ + 3 - S, EYv = S * TY + 3 - S, EXv = S * TX + 3 - S;
    constexpr int NR = EZ * EYv * EXv;
    constexpr int PITCH = (IC == 8) ? 8 : IC + 8;
    constexpr int CHK = IC / 8;
    __shared__ __align__(16) bf16 si[NR * PITCH];
    __shared__ float sw[27 * IC * OC];
    const int ntx = OW / TX, nty = OH / TY;
    const int bx = blockIdx.x % ntx;
    const int by = (blockIdx.x / ntx) % nty;
    const int bz = blockIdx.x / (ntx * nty);
    const int x0 = bx * TX * S - 1, y0 = by * TY * S - 1, z0 = bz * TZ * S - 1;
    for (int i = threadIdx.x; i < 27 * IC * OC; i += TPB) sw[i] = wr[i];
    for (int i = threadIdx.x; i < NR * CHK; i += TPB) {
        int r = i / CHK, c = i % CHK;
        int rx = r % EXv, ry = (r / EXv) % EYv, rz = r / (EXv * EYv);
        int gz = z0 + rz, gy = y0 + ry, gx = x0 + rx;
        uint4 u = make_uint4(0u, 0u, 0u, 0u);
        if ((unsigned)gz < (unsigned)ID && (unsigned)gy < (unsigned)IH &&
            (unsigned)gx < (unsigned)IW)
            u = *(const uint4*)(in + (((long)gz * IH + gy) * IW + gx) * CSin + c * 8);
        *(uint4*)(si + r * PITCH + c * 8) = u;
    }
    __syncthreads();
    constexpr int VX = (TZ * TY * TX) / TPB;
    float acc[VX][OC];
#pragma unroll
    for (int q = 0; q < VX; ++q)
#pragma unroll
        for (int c = 0; c < OC; ++c) acc[q][c] = 0.f;
    int lx[VX], ly[VX], lz[VX];
#pragma unroll
    for (int q = 0; q < VX; ++q) {
        int l = threadIdx.x + q * TPB;
        lx[q] = l % TX; ly[q] = (l / TX) % TY; lz[q] = l / (TX * TY);
    }
#pragma unroll 1
    for (int t = 0; t < 27; ++t) {
        const int kz = t / 9, ky = (t / 3) % 3, kx = t % 3;
        const float* swt = sw + t * IC * OC;
        int ro[VX];
#pragma unroll
        for (int q = 0; q < VX; ++q)
            ro[q] = (((lz[q] * S + kz) * EYv + (ly[q] * S + ky)) * EXv
                     + (lx[q] * S + kx)) * PITCH;
#pragma unroll
        for (int c8 = 0; c8 < IC; c8 += 8) {
            float a[VX][8];
#pragma unroll
            for (int q = 0; q < VX; ++q) ld8(si + ro[q] + c8, a[q]);
#pragma unroll
            for (int j = 0; j < 8; ++j) {
                if constexpr (OC % 4 == 0) {
#pragma unroll
                    for (int c4 = 0; c4 < OC; c4 += 4) {
                        float4 wv = *(const float4*)&swt[(c8 + j) * OC + c4];
#pragma unroll
                        for (int q = 0; q < VX; ++q) {
                            acc[q][c4 + 0] += a[q][j] * wv.x;
                            acc[q][c4 + 1] += a[q][j] * wv.y;
                            acc[q][c4 + 2] += a[q][j] * wv.z;
                            acc[q][c4 + 3] += a[q][j] * wv.w;
                        }
                    }
                } else {
                    float2 wv = *(const float2*)&swt[(c8 + j) * OC];
#pragma unroll
                    for (int q = 0; q < VX; ++q) {
                        acc[q][0] += a[q][j] * wv.x;
                        acc[q][1] += a[q][j] * wv.y;
                    }
                }
            }
        }
    }
#pragma unroll
    for (int q = 0; q < VX; ++q) {
        long vox = ((long)(bz * TZ + lz[q]) * OH + (by * TY + ly[q])) * OW
                   + (bx * TX + lx[q]);
        if constexpr (CFOUT) {
            long Sout = (long)OD * OH * OW;
#pragma unroll
            for (int c = 0; c < OC; ++c) outf[(long)c * Sout + vox] = acc[q][c];
        } else {
            bf16* op = out + vox * CSout;
#pragma unroll
            for (int c8 = 0; c8 < OC; c8 += 8) st8(op + c8, &acc[q][c8]);
        }
    }
}

// ---------------------------------------------------------------------------
// tconv1 tiled: IC=48 -> OC=24, stride-2 transposed conv. Input tile 4x8x8
// (+1 halo) staged once; loops 8 parity classes; per class stages <=4 tap
// weight sets (fp32) at a time. Output 8x16x16 per block into CL rows.
// ---------------------------------------------------------------------------
__global__ __launch_bounds__(TPB) void tconv1_tile_k(
    const bf16* __restrict__ in, const float* __restrict__ wr,
    bf16* __restrict__ out, int ID, int IH, int IW, int CSin, int CSout)
{
    constexpr int IC = 48, OC = 24;
    constexpr int TZ = 4, TY = 8, TX = 8;
    constexpr int EZ = TZ + 1, EY = TY + 1, EX = TX + 1;   // 5,9,9
    constexpr int NR = EZ * EY * EX;                       // 405
    constexpr int PITCH = 56;
    constexpr int CHK = IC / 8;                            // 6
    __shared__ __align__(16) bf16 si[NR * PITCH];          // 45360 B
    __shared__ float sw[4 * IC * OC];                      // 18432 B
    const int ntx = IW / TX, nty = IH / TY;
    const int bx = blockIdx.x % ntx;
    const int by = (blockIdx.x / ntx) % nty;
    const int bz = blockIdx.x / (ntx * nty);
    const int x0 = bx * TX, y0 = by * TY, z0 = bz * TZ;
    for (int i = threadIdx.x; i < NR * CHK; i += TPB) {
        int r = i / CHK, c = i % CHK;
        int rx = r % EX, ry = (r / EX) % EY, rz = r / (EX * EY);
        int gz = z0 + rz, gy = y0 + ry, gx = x0 + rx;
        uint4 u = make_uint4(0u, 0u, 0u, 0u);
        if (gz < ID && gy < IH && gx < IW)
            u = *(const uint4*)(in + (((long)gz * IH + gy) * IW + gx) * CSin + c * 8);
        *(uint4*)(si + r * PITCH + c * 8) = u;
    }
    const int OH = 2 * IH, OW = 2 * IW;
    const int lx = threadIdx.x % TX;
    const int ly = (threadIdx.x / TX) % TY;
    const int lz = threadIdx.x / (TX * TY);
#pragma unroll 1
    for (int cls = 0; cls < 8; ++cls) {
        const int pz = (cls >> 2) & 1, py = (cls >> 1) & 1, px = cls & 1;
        const int ny = 1 + py, nx = 1 + px;
        const int ntap = (1 + pz) * ny * nx;
        float acc[OC];
#pragma unroll
        for (int c = 0; c < OC; ++c) acc[c] = 0.f;
        const int nsub = (ntap + 3) / 4;
#pragma unroll 1
        for (int sub = 0; sub < nsub; ++sub) {
            const int s0 = sub * 4;
            const int scnt = min(4, ntap - s0);
            __syncthreads();   // protects si (first iter) / sw (later iters)
            for (int i = threadIdx.x; i < scnt * IC * OC; i += TPB) {
                int s = s0 + i / (IC * OC);
                int rem = i % (IC * OC);
                int ci = rem / OC, c = rem % OC;
                int a = s / (ny * nx), b = (s / nx) % ny, cc = s % nx;
                int kz = pz ? (a ? 2 : 0) : 1;
                int ky = py ? (b ? 2 : 0) : 1;
                int kx = px ? (cc ? 2 : 0) : 1;
                sw[i] = wr[((kz * 9 + ky * 3 + kx) * IC + ci) * OC + c];
            }
            __syncthreads();
#pragma unroll 1
            for (int sidx = 0; sidx < scnt; ++sidx) {
                int s = s0 + sidx;
                int a = s / (ny * nx), b = (s / nx) % ny, cc = s % nx;
                int dz = pz ? a : 0, dy = py ? b : 0, dx = px ? cc : 0;
                const float* swt = sw + sidx * IC * OC;
                const int ro = (((lz + dz) * EY + (ly + dy)) * EX + (lx + dx)) * PITCH;
#pragma unroll
                for (int c8 = 0; c8 < IC; c8 += 8) {
                    float a8[8];
                    ld8(si + ro + c8, a8);
#pragma unroll
                    for (int j = 0; j < 8; ++j)
#pragma unroll
                        for (int c4 = 0; c4 < OC; c4 += 4) {
                            float4 wv = *(const float4*)&swt[(c8 + j) * OC + c4];
                            acc[c4 + 0] += a8[j] * wv.x;
                            acc[c4 + 1] += a8[j] * wv.y;
                            acc[c4 + 2] += a8[j] * wv.z;
                            acc[c4 + 3] += a8[j] * wv.w;
                        }
                }
            }
        }
        const int z = 2 * (z0 + lz) + pz;
        const int y = 2 * (y0 + ly) + py;
        const int xx = 2 * (x0 + lx) + px;
        long vout = ((long)z * OH + y) * OW + xx;
        bf16* op = out + vout * CSout;
#pragma unroll
        for (int c8 = 0; c8 < OC; c8 += 8) st8(op + c8, &acc[c8]);
    }
}

// ---------------------------------------------------------------------------
// UNTILED channels-last conv (kept for small layers: conv2, conv3).
// ---------------------------------------------------------------------------
template <int IC, int OCT, int VX, int STRIDE, bool CFOUT>
__global__ __launch_bounds__(TPB) void conv_cl_k(
    const bf16* __restrict__ in, const float* __restrict__ wr,
    bf16* __restrict__ out, float* __restrict__ outf,
    int ID, int IH, int IW, int OD, int OH, int OW,
    int CSin, int CSout, int OC)
{
    __shared__ float sw[27 * IC * OCT];
    const int cog0 = blockIdx.y * OCT;
    for (int i = threadIdx.x; i < 27 * IC * OCT; i += TPB) {
        int t_ci = i / OCT, c = i % OCT;
        sw[i] = wr[t_ci * OC + cog0 + c];
    }
    __syncthreads();

    const long S = (long)OD * OH * OW;
    long v[VX]; int xx[VX], yy[VX], zz[VX]; bool ok[VX];
    const long vb = (long)blockIdx.x * (TPB * VX) + threadIdx.x;
#pragma unroll
    for (int q = 0; q < VX; ++q) {
        v[q] = vb + (long)q * TPB;
        ok[q] = v[q] < S;
        long vv = ok[q] ? v[q] : 0;
        xx[q] = (int)(vv % OW); yy[q] = (int)((vv / OW) % OH);
        zz[q] = (int)(vv / ((long)OW * OH));
    }
    float acc[VX][OCT];
#pragma unroll
    for (int q = 0; q < VX; ++q)
#pragma unroll
        for (int c = 0; c < OCT; ++c) acc[q][c] = 0.f;

#pragma unroll 1
    for (int t = 0; t < 27; ++t) {
        const int kz = t / 9, ky = (t / 3) % 3, kx = t % 3;
        const float* swt = sw + t * IC * OCT;
        long bi[VX]; bool val[VX];
#pragma unroll
        for (int q = 0; q < VX; ++q) {
            int iz = zz[q] * STRIDE - 1 + kz;
            int iy = yy[q] * STRIDE - 1 + ky;
            int ix = xx[q] * STRIDE - 1 + kx;
            val[q] = ok[q] && (unsigned)iz < (unsigned)ID && (unsigned)iy < (unsigned)IH
                     && (unsigned)ix < (unsigned)IW;
            bi[q] = (((long)iz * IH + iy) * IW + ix) * CSin;
        }
#pragma unroll 1
        for (int c8 = 0; c8 < IC; c8 += 8) {
            float a[VX][8];
#pragma unroll
            for (int q = 0; q < VX; ++q) {
                if (val[q]) ld8(in + bi[q] + c8, a[q]); else zero8(a[q]);
            }
#pragma unroll
            for (int j = 0; j < 8; ++j) {
#pragma unroll
                for (int c4 = 0; c4 < OCT; c4 += 4) {
                    float4 wv = *(const float4*)&swt[(c8 + j) * OCT + c4];
#pragma unroll
                    for (int q = 0; q < VX; ++q) {
                        acc[q][c4 + 0] += a[q][j] * wv.x;
                        acc[q][c4 + 1] += a[q][j] * wv.y;
                        acc[q][c4 + 2] += a[q][j] * wv.z;
                        acc[q][c4 + 3] += a[q][j] * wv.w;
                    }
                }
            }
        }
    }
#pragma unroll
    for (int q = 0; q < VX; ++q) {
        if (!ok[q]) continue;
        bf16* op = out + v[q] * CSout + cog0;
#pragma unroll
        for (int c8 = 0; c8 < OCT; c8 += 8) st8(op + c8, &acc[q][c8]);
    }
}

// ---------------------------------------------------------------------------
// UNTILED transposed conv (kept for tconv3, tconv2 — L2-resident inputs).
// ---------------------------------------------------------------------------
template <int IC, int OCT, int VX>
__global__ __launch_bounds__(TPB) void tconv_cl_k(
    const bf16* __restrict__ in, const float* __restrict__ wr,
    bf16* __restrict__ out,
    int ID, int IH, int IW, int CSin, int CSout, int OC)
{
    const int cls = blockIdx.z;
    const int pz = (cls >> 2) & 1, py = (cls >> 1) & 1, px = cls & 1;
    const int nz = 1 + pz, ny = 1 + py, nx = 1 + px;
    const int ntap = nz * ny * nx;

    __shared__ float sw[8 * IC * OCT];
    const int cog0 = blockIdx.y * OCT;
    for (int i = threadIdx.x; i < ntap * IC * OCT; i += TPB) {
        int s = i / (IC * OCT);
        int rem = i % (IC * OCT);
        int ci = rem / OCT, c = rem % OCT;
        int a = s / (ny * nx), b = (s / nx) % ny, cc = s % nx;
        int kz = pz ? (a ? 2 : 0) : 1;
        int ky = py ? (b ? 2 : 0) : 1;
        int kx = px ? (cc ? 2 : 0) : 1;
        sw[i] = wr[((kz * 9 + ky * 3 + kx) * IC + ci) * OC + cog0 + c];
    }
    __syncthreads();

    const int OH = 2 * IH, OW = 2 * IW;
    const long SUB = (long)ID * IH * IW;
    long vi[VX]; int xi[VX], yi[VX], zi[VX]; bool ok[VX];
    const long vb = (long)blockIdx.x * (TPB * VX) + threadIdx.x;
#pragma unroll
    for (int q = 0; q < VX; ++q) {
        vi[q] = vb + (long)q * TPB;
        ok[q] = vi[q] < SUB;
        long vv = ok[q] ? vi[q] : 0;
        xi[q] = (int)(vv % IW); yi[q] = (int)((vv / IW) % IH);
        zi[q] = (int)(vv / ((long)IW * IH));
    }
    float acc[VX][OCT];
#pragma unroll
    for (int q = 0; q < VX; ++q)
#pragma unroll
        for (int c = 0; c < OCT; ++c) acc[q][c] = 0.f;

#pragma unroll 1
    for (int s = 0; s < ntap; ++s) {
        int a = s / (ny * nx), b = (s / nx) % ny, cc = s % nx;
        int dz = pz ? a : 0, dy = py ? b : 0, dx = px ? cc : 0;
        const float* swt = sw + s * IC * OCT;
        long bi[VX]; bool val[VX];
#pragma unroll
        for (int q = 0; q < VX; ++q) {
            int iz = zi[q] + dz, iy = yi[q] + dy, ix = xi[q] + dx;
            val[q] = ok[q] && iz < ID && iy < IH && ix < IW;
            bi[q] = (((long)iz * IH + iy) * IW + ix) * CSin;
        }
#pragma unroll 1
        for (int c8 = 0; c8 < IC; c8 += 8) {
            float a8[VX][8];
#pragma unroll
            for (int q = 0; q < VX; ++q) {
                if (val[q]) ld8(in + bi[q] + c8, a8[q]); else zero8(a8[q]);
            }
#pragma unroll
            for (int j = 0; j < 8; ++j)
#pragma unroll
                for (int c4 = 0; c4 < OCT; c4 += 4) {
                    float4 wv = *(const float4*)&swt[(c8 + j) * OCT + c4];
#pragma unroll
                    for (int q = 0; q < VX; ++q) {
                        acc[q][c4 + 0] += a8[q][j] * wv.x;
                        acc[q][c4 + 1] += a8[q][j] * wv.y;
                        acc[q][c4 + 2] += a8[q][j] * wv.z;
                        acc[q][c4 + 3] += a8[q][j] * wv.w;
                    }
                }
        }
    }
#pragma unroll
    for (int q = 0; q < VX; ++q) {
        if (!ok[q]) continue;
        int z = 2 * zi[q] + pz, y = 2 * yi[q] + py, x = 2 * xi[q] + px;
        long vout = ((long)z * OH + y) * OW + x;
        bf16* op = out + vout * CSout + cog0;
#pragma unroll
        for (int c8 = 0; c8 < OCT; c8 += 8) st8(op + c8, &acc[q][c8]);
    }
}

// ---------------------------------------------------------------------------
// Per-channel-group {sum,sumsq} over channels-last buffer. CG=8.
// ---------------------------------------------------------------------------
__global__ __launch_bounds__(TPB) void reduce_cl_k(
    const bf16* __restrict__ buf, long spatial, int CS, float* __restrict__ stats)
{
    const int g0 = blockIdx.y * 8;
    float s[8], s2[8];
#pragma unroll
    for (int c = 0; c < 8; ++c) { s[c] = 0.f; s2[c] = 0.f; }
    for (long v = (long)blockIdx.x * TPB + threadIdx.x; v < spatial;
         v += (long)gridDim.x * TPB) {
        float a[8];
        ld8(buf + v * CS + g0, a);
#pragma unroll
        for (int c = 0; c < 8; ++c) { s[c] += a[c]; s2[c] += a[c] * a[c]; }
    }
#pragma unroll
    for (int c = 0; c < 8; ++c)
        for (int off = 32; off > 0; off >>= 1) {
            s[c]  += __shfl_down(s[c], off, 64);
            s2[c] += __shfl_down(s2[c], off, 64);
        }
    if ((threadIdx.x & 63) == 0) {
#pragma unroll
        for (int c = 0; c < 8; ++c) {
            atomicAdd(&stats[2 * (g0 + c)],     s[c]);
            atomicAdd(&stats[2 * (g0 + c) + 1], s2[c]);
        }
    }
}

// ---------------------------------------------------------------------------
// In-place BN+ReLU on channels-last bf16. CG=8.
// ---------------------------------------------------------------------------
__global__ __launch_bounds__(TPB) void bnrelu_cl_k(
    bf16* __restrict__ buf, long spatial, int CS,
    const float* __restrict__ stats, const float* __restrict__ g,
    const float* __restrict__ b, float invN)
{
    const int g0 = blockIdx.y * 8;
    float sc[8], sh[8];
#pragma unroll
    for (int c = 0; c < 8; ++c) {
        float mean = stats[2 * (g0 + c)] * invN;
        float var  = stats[2 * (g0 + c) + 1] * invN - mean * mean;
        sc[c] = rsqrtf(var + 1e-5f) * g[g0 + c];
        sh[c] = b[g0 + c] - mean * sc[c];
    }
    for (long v = (long)blockIdx.x * TPB + threadIdx.x; v < spatial;
         v += (long)gridDim.x * TPB) {
        bf16* p = buf + v * CS + g0;
        float a[8];
        ld8(p, a);
#pragma unroll
        for (int c = 0; c < 8; ++c) {
            float t = a[c] * sc[c] + sh[c];
            a[c] = t > 0.f ? t : 0.f;
        }
        st8(p, a);
    }
}

static inline int nblocks(long n, int per) { return (int)((n + per - 1) / per); }

extern "C" void kernel_launch(void* const* d_in, const int* in_sizes, int n_in,
                              void* d_out, int out_size, void* d_ws, size_t ws_size,
                              hipStream_t stream)
{
    const float* x    = (const float*)d_in[0];
    const float* w0   = (const float*)d_in[1];
    const float* g0   = (const float*)d_in[2];
    const float* b0   = (const float*)d_in[3];
    const float* w1   = (const float*)d_in[4];
    const float* g1   = (const float*)d_in[5];
    const float* b1   = (const float*)d_in[6];
    const float* w2   = (const float*)d_in[7];
    const float* g2   = (const float*)d_in[8];
    const float* b2   = (const float*)d_in[9];
    const float* w3   = (const float*)d_in[10];
    const float* g3   = (const float*)d_in[11];
    const float* b3   = (const float*)d_in[12];
    const float* wt3  = (const float*)d_in[13];
    const float* gt3  = (const float*)d_in[14];
    const float* bt3  = (const float*)d_in[15];
    const float* wt2  = (const float*)d_in[16];
    const float* gt2  = (const float*)d_in[17];
    const float* bt2  = (const float*)d_in[18];
    const float* wt1  = (const float*)d_in[19];
    const float* gt1  = (const float*)d_in[20];
    const float* bt1  = (const float*)d_in[21];
    const float* wout = (const float*)d_in[22];

    const long S128 = 128L * 128 * 128;
    const long S64  = 64L * 64 * 64;
    const long S32  = 32L * 32 * 32;
    const long S16  = 16L * 16 * 16;

    // ---- workspace (identical layout to passing round) ----
    float* stats = (float*)d_ws;             // 512 floats (cumulative offsets)
    float* wro   = stats + 512;              // 1728 floats (out-conv weights)
    bf16* base = (bf16*)((char*)d_ws + (512 + 1728) * 4);
    bf16* cat1 = base;                 // [128^3][32]: ch0-23 tconv1, ch24-31 s1
    bf16* cat2 = cat1 + S128 * 32;     // [64^3][48] : ch0-31 tconv2, ch32-47 s2
    bf16* cat3 = cat2 + S64 * 48;      // [32^3][64] : ch0-31 tconv3, ch32-63 s4
    bf16* s8   = cat3 + S32 * 64;      // [16^3][64]
    bf16* s1 = cat1 + 24;
    bf16* s2 = cat2 + 32;
    bf16* s4 = cat3 + 32;

    // repacked weights live in d_out (consumed before conv_out overwrites it)
    float* wrd  = (float*)d_out;
    float* wr0  = wrd;            // 1728
    float* wr1  = wrd + 1728;     // 3456
    float* wr2  = wrd + 5184;     // 13824
    float* wr3  = wrd + 19008;    // 55296
    float* wrt3 = wrd + 74304;    // 55296
    float* wrt2 = wrd + 129600;   // 55296
    float* wrt1 = wrd + 184896;   // 31104 (end 216000 floats = 864 KB)

    repack_w_k<<<nblocks(1728, TPB),  TPB, 0, stream>>>(w0,  wr0,  8, 8);
    repack_w_k<<<nblocks(3456, TPB),  TPB, 0, stream>>>(w1,  wr1,  16, 8);
    repack_w_k<<<nblocks(13824, TPB), TPB, 0, stream>>>(w2,  wr2,  32, 16);
    repack_w_k<<<nblocks(55296, TPB), TPB, 0, stream>>>(w3,  wr3,  64, 32);
    repack_w_k<<<nblocks(55296, TPB), TPB, 0, stream>>>(wt3, wrt3, 32, 64);
    repack_w_k<<<nblocks(55296, TPB), TPB, 0, stream>>>(wt2, wrt2, 32, 64);
    repack_w_k<<<nblocks(31104, TPB), TPB, 0, stream>>>(wt1, wrt1, 24, 48);
    repack_w_k<<<nblocks(1728, TPB),  TPB, 0, stream>>>(wout, wro, 2, 32);

    hipMemsetAsync(stats, 0, 512 * sizeof(float), stream);

    // ---- encoder ----
    // conv0 tiled: x fp32 [8][128^3] -> s1 (cat1 ch24-31). 4096 tiles of 8^3.
    conv0_tile_k<8, 8, 8><<<4096, TPB, 0, stream>>>(x, wr0, s1, 32);
    reduce_cl_k<<<dim3(512, 1), TPB, 0, stream>>>(s1, S128, 32, stats + 0);
    bnrelu_cl_k<<<dim3(1024, 1), TPB, 0, stream>>>(s1, S128, 32, stats + 0, g0, b0, 1.f / S128);

    // conv1 tiled: s1 (IC=8) -> s2 (OC=16), stride2 128->64. tiles 4x8x8 => 1024
    conv_tile_k<8, 16, 2, 4, 8, 8, false><<<1024, TPB, 0, stream>>>(
        s1, wr1, s2, nullptr, 128, 128, 128, 64, 64, 64, 32, 48);
    reduce_cl_k<<<dim3(256, 2), TPB, 0, stream>>>(s2, S64, 48, stats + 16);
    bnrelu_cl_k<<<dim3(256, 2), TPB, 0, stream>>>(s2, S64, 48, stats + 16, g1, b1, 1.f / S64);

    // conv2 (untiled): s2 (IC=16) -> s4 (OC=32), stride2 64->32
    conv_cl_k<16, 16, 2, 2, false><<<dim3(nblocks(S32, TPB * 2), 2), TPB, 0, stream>>>(
        s2, wr2, s4, nullptr, 64, 64, 64, 32, 32, 32, 48, 64, 32);
    reduce_cl_k<<<dim3(64, 4), TPB, 0, stream>>>(s4, S32, 64, stats + 48);
    bnrelu_cl_k<<<dim3(64, 4), TPB, 0, stream>>>(s4, S32, 64, stats + 48, g2, b2, 1.f / S32);

    // conv3 (untiled): s4 (IC=32) -> s8 (OC=64), stride2 32->16
    conv_cl_k<32, 8, 1, 2, false><<<dim3(nblocks(S16, TPB), 8), TPB, 0, stream>>>(
        s4, wr3, s8, nullptr, 32, 32, 32, 16, 16, 16, 64, 64, 64);
    reduce_cl_k<<<dim3(16, 8), TPB, 0, stream>>>(s8, S16, 64, stats + 112);
    bnrelu_cl_k<<<dim3(16, 8), TPB, 0, stream>>>(s8, S16, 64, stats + 112, g3, b3, 1.f / S16);

    // ---- decoder ----
    // tconv3 (untiled): s8 (IC=64) -> cat3 ch0-31 (OC=32), 16->32
    tconv_cl_k<64, 16, 1><<<dim3(nblocks(S16, TPB), 2, 8), TPB, 0, stream>>>(
        s8, wrt3, cat3, 16, 16, 16, 64, 64, 32);
    reduce_cl_k<<<dim3(64, 4), TPB, 0, stream>>>(cat3, S32, 64, stats + 240);
    bnrelu_cl_k<<<dim3(64, 4), TPB, 0, stream>>>(cat3, S32, 64, stats + 240, gt3, bt3, 1.f / S32);

    // tconv2 (untiled): cat3 (IC=64) -> cat2 ch0-31 (OC=32), 32->64
    tconv_cl_k<64, 16, 1><<<dim3(nblocks(S32, TPB), 2, 8), TPB, 0, stream>>>(
        cat3, wrt2, cat2, 32, 32, 32, 64, 48, 32);
    reduce_cl_k<<<dim3(256, 4), TPB, 0, stream>>>(cat2, S64, 48, stats + 304);
    bnrelu_cl_k<<<dim3(256, 4), TPB, 0, stream>>>(cat2, S64, 48, stats + 304, gt2, bt2, 1.f / S64);

    // tconv1 tiled: cat2 (IC=48) -> cat1 ch0-23 (OC=24), 64->128. 1024 tiles.
    tconv1_tile_k<<<1024, TPB, 0, stream>>>(cat2, wrt1, cat1, 64, 64, 64, 48, 32);
    reduce_cl_k<<<dim3(512, 3), TPB, 0, stream>>>(cat1, S128, 32, stats + 368);
    bnrelu_cl_k<<<dim3(512, 3), TPB, 0, stream>>>(cat1, S128, 32, stats + 368, gt1, bt1, 1.f / S128);

    // out conv tiled: cat1 (IC=32) -> d_out fp32 [2][128^3]. tiles 4x8x8 => 8192
    conv_tile_k<32, 2, 1, 4, 8, 8, true><<<8192, TPB, 0, stream>>>(
        cat1, wro, nullptr, (float*)d_out, 128, 128, 128, 128, 128, 128, 32, 0);
}

// Round 6
// 1548.962 us; speedup vs baseline: 7.1499x; 2.1982x over previous
//
#include <hip/hip_runtime.h>
#include <hip/hip_bf16.h>

typedef __hip_bfloat16 bf16;
#define TPB 256

// ---- bf16x8 vector helpers (16B) ----
__device__ inline void ld8(const bf16* p, float* v) {
    uint4 u = *(const uint4*)p;
    const unsigned short* s = (const unsigned short*)&u;
#pragma unroll
    for (int j = 0; j < 8; ++j) v[j] = __uint_as_float((unsigned)s[j] << 16);
}
__device__ inline void zero8(float* v) {
#pragma unroll
    for (int j = 0; j < 8; ++j) v[j] = 0.f;
}
__device__ inline void st8(bf16* p, const float* v) {
    bf16 t[8];
#pragma unroll
    for (int j = 0; j < 8; ++j) t[j] = __float2bfloat16(v[j]);
    *(uint4*)p = *(const uint4*)t;
}
__device__ inline void wred2(float& a, float& b) {
#pragma unroll
    for (int o = 32; o > 0; o >>= 1) {
        a += __shfl_down(a, o, 64);
        b += __shfl_down(b, o, 64);
    }
}

// ---------------------------------------------------------------------------
// Weight repack: w [OC][IC][27] -> wr [27][IC][OC]  (fp32)
// ---------------------------------------------------------------------------
__global__ __launch_bounds__(TPB) void repack_w_k(
    const float* __restrict__ w, float* __restrict__ wr, int OC, int IC)
{
    int idx = blockIdx.x * TPB + threadIdx.x;
    int n = OC * IC * 27;
    if (idx >= n) return;
    int co = idx / (IC * 27);
    int ci = (idx / 27) % IC;
    int t  = idx % 27;
    wr[(t * IC + ci) * OC + co] = w[idx];
}

// ---------------------------------------------------------------------------
// sumcol: fold column-major partials [col][nrow] -> stats[col]. 1 block/col.
// ---------------------------------------------------------------------------
__global__ __launch_bounds__(64) void sumcol_k(
    const float* __restrict__ p, int nrow, float* __restrict__ out)
{
    const long col = blockIdx.x;
    float s = 0.f;
    for (int r = threadIdx.x; r < nrow; r += 64) s += p[col * nrow + r];
    float d = 0.f;
    wred2(s, d);
    if (threadIdx.x == 0) out[col] = s;
}

// ---------------------------------------------------------------------------
// conv0 tiled: fp32 NCDHW input [8][128^3], stride 1, LDS tile, fused stats.
// ---------------------------------------------------------------------------
template <int TZ, int TY, int TX>
__global__ __launch_bounds__(TPB) void conv0_tile_k(
    const float* __restrict__ x, const float* __restrict__ wr,
    bf16* __restrict__ out, int CSout, float* __restrict__ prt, int nrow)
{
    const int D = 128;
    const long S = (long)D * D * D;
    constexpr int EZ = TZ + 2, EY = TY + 2, EX = TX + 2;
    constexpr int NR = EZ * EY * EX;
    __shared__ __align__(16) bf16 si[NR * 8];
    __shared__ float sw[27 * 64];
    __shared__ float ps[4][16];
    const int ntx = D / TX, nty = D / TY;
    const int bx = blockIdx.x % ntx;
    const int by = (blockIdx.x / ntx) % nty;
    const int bz = blockIdx.x / (ntx * nty);
    const int x0 = bx * TX - 1, y0 = by * TY - 1, z0 = bz * TZ - 1;
    for (int i = threadIdx.x; i < 27 * 64; i += TPB) sw[i] = wr[i];
    for (int i = threadIdx.x; i < NR * 8; i += TPB) {
        int c = i / NR, r = i % NR;
        int rx = r % EX, ry = (r / EX) % EY, rz = r / (EX * EY);
        int gz = z0 + rz, gy = y0 + ry, gx = x0 + rx;
        float v = 0.f;
        if ((unsigned)gz < (unsigned)D && (unsigned)gy < (unsigned)D &&
            (unsigned)gx < (unsigned)D)
            v = x[(long)c * S + ((long)gz * D + gy) * D + gx];
        si[r * 8 + c] = __float2bfloat16(v);
    }
    __syncthreads();
    constexpr int VX = (TZ * TY * TX) / TPB;
    float acc[VX][8];
#pragma unroll
    for (int q = 0; q < VX; ++q) zero8(acc[q]);
    int lx[VX], ly[VX], lz[VX];
#pragma unroll
    for (int q = 0; q < VX; ++q) {
        int l = threadIdx.x + q * TPB;
        lx[q] = l % TX; ly[q] = (l / TX) % TY; lz[q] = l / (TX * TY);
    }
#pragma unroll 1
    for (int t = 0; t < 27; ++t) {
        const int kz = t / 9, ky = (t / 3) % 3, kx = t % 3;
        const float* swt = sw + t * 64;
        float a[VX][8];
#pragma unroll
        for (int q = 0; q < VX; ++q) {
            int r = ((lz[q] + kz) * EY + (ly[q] + ky)) * EX + (lx[q] + kx);
            ld8(si + r * 8, a[q]);
        }
#pragma unroll
        for (int j = 0; j < 8; ++j)
#pragma unroll
            for (int c4 = 0; c4 < 8; c4 += 4) {
                float4 wv = *(const float4*)&swt[j * 8 + c4];
#pragma unroll
                for (int q = 0; q < VX; ++q) {
                    acc[q][c4 + 0] += a[q][j] * wv.x;
                    acc[q][c4 + 1] += a[q][j] * wv.y;
                    acc[q][c4 + 2] += a[q][j] * wv.z;
                    acc[q][c4 + 3] += a[q][j] * wv.w;
                }
            }
    }
#pragma unroll
    for (int q = 0; q < VX; ++q) {
        long vox = ((long)(bz * TZ + lz[q]) * D + (by * TY + ly[q])) * D
                   + (bx * TX + lx[q]);
        st8(out + vox * CSout, acc[q]);
    }
    // fused stats
    const int w = threadIdx.x >> 6, lane = threadIdx.x & 63;
#pragma unroll
    for (int c = 0; c < 8; ++c) {
        float t = 0.f, t2 = 0.f;
#pragma unroll
        for (int q = 0; q < VX; ++q) { t += acc[q][c]; t2 += acc[q][c] * acc[q][c]; }
        wred2(t, t2);
        if (lane == 0) { ps[w][2 * c] = t; ps[w][2 * c + 1] = t2; }
    }
    __syncthreads();
    if (threadIdx.x < 16) {
        float v = ps[0][threadIdx.x] + ps[1][threadIdx.x] + ps[2][threadIdx.x]
                + ps[3][threadIdx.x];
        prt[(long)threadIdx.x * nrow + blockIdx.x] = v;
    }
}

// ---------------------------------------------------------------------------
// Tiled channels-last conv, k=3, pad 1, stride S, LDS-staged, fused stats.
// CFOUT=true -> fp32 channel-first output (no stats).
// ---------------------------------------------------------------------------
template <int IC, int OC, int S, int TZ, int TY, int TX, bool CFOUT, bool DOSTATS>
__global__ __launch_bounds__(TPB) void conv_tile_k(
    const bf16* __restrict__ in, const float* __restrict__ wr,
    bf16* __restrict__ out, float* __restrict__ outf,
    int ID, int IH, int IW, int OD, int OH, int OW, int CSin, int CSout,
    float* __restrict__ prt, int nrow)
{
    constexpr int EZ = S * TZ + 3 - S, EYv = S * TY + 3 - S, EXv = S * TX + 3 - S;
    constexpr int NR = EZ * EYv * EXv;
    constexpr int PITCH = (IC == 8) ? 8 : IC + 8;
    constexpr int CHK = IC / 8;
    __shared__ __align__(16) bf16 si[NR * PITCH];
    __shared__ float sw[27 * IC * OC];
    __shared__ float ps[4][2 * OC];
    const int ntx = OW / TX, nty = OH / TY;
    const int bx = blockIdx.x % ntx;
    const int by = (blockIdx.x / ntx) % nty;
    const int bz = blockIdx.x / (ntx * nty);
    const int x0 = bx * TX * S - 1, y0 = by * TY * S - 1, z0 = bz * TZ * S - 1;
    for (int i = threadIdx.x; i < 27 * IC * OC; i += TPB) sw[i] = wr[i];
    for (int i = threadIdx.x; i < NR * CHK; i += TPB) {
        int r = i / CHK, c = i % CHK;
        int rx = r % EXv, ry = (r / EXv) % EYv, rz = r / (EXv * EYv);
        int gz = z0 + rz, gy = y0 + ry, gx = x0 + rx;
        uint4 u = make_uint4(0u, 0u, 0u, 0u);
        if ((unsigned)gz < (unsigned)ID && (unsigned)gy < (unsigned)IH &&
            (unsigned)gx < (unsigned)IW)
            u = *(const uint4*)(in + (((long)gz * IH + gy) * IW + gx) * CSin + c * 8);
        *(uint4*)(si + r * PITCH + c * 8) = u;
    }
    __syncthreads();
    constexpr int VX = (TZ * TY * TX) / TPB;
    float acc[VX][OC];
#pragma unroll
    for (int q = 0; q < VX; ++q)
#pragma unroll
        for (int c = 0; c < OC; ++c) acc[q][c] = 0.f;
    int lx[VX], ly[VX], lz[VX];
#pragma unroll
    for (int q = 0; q < VX; ++q) {
        int l = threadIdx.x + q * TPB;
        lx[q] = l % TX; ly[q] = (l / TX) % TY; lz[q] = l / (TX * TY);
    }
#pragma unroll 1
    for (int t = 0; t < 27; ++t) {
        const int kz = t / 9, ky = (t / 3) % 3, kx = t % 3;
        const float* swt = sw + t * IC * OC;
        int ro[VX];
#pragma unroll
        for (int q = 0; q < VX; ++q)
            ro[q] = (((lz[q] * S + kz) * EYv + (ly[q] * S + ky)) * EXv
                     + (lx[q] * S + kx)) * PITCH;
#pragma unroll
        for (int c8 = 0; c8 < IC; c8 += 8) {
            float a[VX][8];
#pragma unroll
            for (int q = 0; q < VX; ++q) ld8(si + ro[q] + c8, a[q]);
#pragma unroll
            for (int j = 0; j < 8; ++j) {
                if constexpr (OC % 4 == 0) {
#pragma unroll
                    for (int c4 = 0; c4 < OC; c4 += 4) {
                        float4 wv = *(const float4*)&swt[(c8 + j) * OC + c4];
#pragma unroll
                        for (int q = 0; q < VX; ++q) {
                            acc[q][c4 + 0] += a[q][j] * wv.x;
                            acc[q][c4 + 1] += a[q][j] * wv.y;
                            acc[q][c4 + 2] += a[q][j] * wv.z;
                            acc[q][c4 + 3] += a[q][j] * wv.w;
                        }
                    }
                } else {
                    float2 wv = *(const float2*)&swt[(c8 + j) * OC];
#pragma unroll
                    for (int q = 0; q < VX; ++q) {
                        acc[q][0] += a[q][j] * wv.x;
                        acc[q][1] += a[q][j] * wv.y;
                    }
                }
            }
        }
    }
#pragma unroll
    for (int q = 0; q < VX; ++q) {
        long vox = ((long)(bz * TZ + lz[q]) * OH + (by * TY + ly[q])) * OW
                   + (bx * TX + lx[q]);
        if constexpr (CFOUT) {
            long Sout = (long)OD * OH * OW;
#pragma unroll
            for (int c = 0; c < OC; ++c) outf[(long)c * Sout + vox] = acc[q][c];
        } else {
            bf16* op = out + vox * CSout;
#pragma unroll
            for (int c8 = 0; c8 < OC; c8 += 8) st8(op + c8, &acc[q][c8]);
        }
    }
    if constexpr (DOSTATS) {
        const int w = threadIdx.x >> 6, lane = threadIdx.x & 63;
#pragma unroll
        for (int c = 0; c < OC; ++c) {
            float t = 0.f, t2 = 0.f;
#pragma unroll
            for (int q = 0; q < VX; ++q) { t += acc[q][c]; t2 += acc[q][c] * acc[q][c]; }
            wred2(t, t2);
            if (lane == 0) { ps[w][2 * c] = t; ps[w][2 * c + 1] = t2; }
        }
        __syncthreads();
        if (threadIdx.x < 2 * OC) {
            float v = ps[0][threadIdx.x] + ps[1][threadIdx.x] + ps[2][threadIdx.x]
                    + ps[3][threadIdx.x];
            prt[(long)threadIdx.x * nrow + blockIdx.x] = v;
        }
    }
}

// ---------------------------------------------------------------------------
// tconv1 tiled: IC=48 -> OC=24. Input tile 4x8x8 (+1 halo) staged once;
// loops 8 parity classes; stages <=3 tap weight sets at a time. Fused stats
// accumulated across classes in LDS, one partial write per block.
// ---------------------------------------------------------------------------
__global__ __launch_bounds__(TPB) void tconv1_tile_k(
    const bf16* __restrict__ in, const float* __restrict__ wr,
    bf16* __restrict__ out, int ID, int IH, int IW, int CSin, int CSout,
    float* __restrict__ prt, int nrow)
{
    constexpr int IC = 48, OC = 24;
    constexpr int TZ = 4, TY = 8, TX = 8;
    constexpr int EZ = TZ + 1, EY = TY + 1, EX = TX + 1;   // 5,9,9
    constexpr int NR = EZ * EY * EX;                       // 405
    constexpr int PITCH = 56;
    constexpr int CHK = IC / 8;                            // 6
    __shared__ __align__(16) bf16 si[NR * PITCH];          // 45360 B
    __shared__ float sw[3 * IC * OC];                      // 13824 B
    __shared__ float ps[4][48];                            // 768 B
    const int ntx = IW / TX, nty = IH / TY;
    const int bx = blockIdx.x % ntx;
    const int by = (blockIdx.x / ntx) % nty;
    const int bz = blockIdx.x / (ntx * nty);
    const int x0 = bx * TX, y0 = by * TY, z0 = bz * TZ;
    const int w = threadIdx.x >> 6, lane = threadIdx.x & 63;
    if (lane == 0)
#pragma unroll
        for (int j = 0; j < 48; ++j) ps[w][j] = 0.f;
    for (int i = threadIdx.x; i < NR * CHK; i += TPB) {
        int r = i / CHK, c = i % CHK;
        int rx = r % EX, ry = (r / EX) % EY, rz = r / (EX * EY);
        int gz = z0 + rz, gy = y0 + ry, gx = x0 + rx;
        uint4 u = make_uint4(0u, 0u, 0u, 0u);
        if (gz < ID && gy < IH && gx < IW)
            u = *(const uint4*)(in + (((long)gz * IH + gy) * IW + gx) * CSin + c * 8);
        *(uint4*)(si + r * PITCH + c * 8) = u;
    }
    const int OH = 2 * IH, OW = 2 * IW;
    const int lx = threadIdx.x % TX;
    const int ly = (threadIdx.x / TX) % TY;
    const int lz = threadIdx.x / (TX * TY);
#pragma unroll 1
    for (int cls = 0; cls < 8; ++cls) {
        const int pz = (cls >> 2) & 1, py = (cls >> 1) & 1, px = cls & 1;
        const int ny = 1 + py, nx = 1 + px;
        const int ntap = (1 + pz) * ny * nx;
        float acc[OC];
#pragma unroll
        for (int c = 0; c < OC; ++c) acc[c] = 0.f;
        const int nsub = (ntap + 2) / 3;
#pragma unroll 1
        for (int sub = 0; sub < nsub; ++sub) {
            const int s0 = sub * 3;
            const int scnt = min(3, ntap - s0);
            __syncthreads();   // protects si (first iter) / sw (later iters)
            for (int i = threadIdx.x; i < scnt * IC * OC; i += TPB) {
                int s = s0 + i / (IC * OC);
                int rem = i % (IC * OC);
                int ci = rem / OC, c = rem % OC;
                int a = s / (ny * nx), b = (s / nx) % ny, cc = s % nx;
                int kz = pz ? (a ? 2 : 0) : 1;
                int ky = py ? (b ? 2 : 0) : 1;
                int kx = px ? (cc ? 2 : 0) : 1;
                sw[i] = wr[((kz * 9 + ky * 3 + kx) * IC + ci) * OC + c];
            }
            __syncthreads();
#pragma unroll 1
            for (int sidx = 0; sidx < scnt; ++sidx) {
                int s = s0 + sidx;
                int a = s / (ny * nx), b = (s / nx) % ny, cc = s % nx;
                int dz = pz ? a : 0, dy = py ? b : 0, dx = px ? cc : 0;
                const float* swt = sw + sidx * IC * OC;
                const int ro = (((lz + dz) * EY + (ly + dy)) * EX + (lx + dx)) * PITCH;
#pragma unroll
                for (int c8 = 0; c8 < IC; c8 += 8) {
                    float a8[8];
                    ld8(si + ro + c8, a8);
#pragma unroll
                    for (int j = 0; j < 8; ++j)
#pragma unroll
                        for (int c4 = 0; c4 < OC; c4 += 4) {
                            float4 wv = *(const float4*)&swt[(c8 + j) * OC + c4];
                            acc[c4 + 0] += a8[j] * wv.x;
                            acc[c4 + 1] += a8[j] * wv.y;
                            acc[c4 + 2] += a8[j] * wv.z;
                            acc[c4 + 3] += a8[j] * wv.w;
                        }
                }
            }
        }
        const int z = 2 * (z0 + lz) + pz;
        const int y = 2 * (y0 + ly) + py;
        const int xx = 2 * (x0 + lx) + px;
        long vout = ((long)z * OH + y) * OW + xx;
        bf16* op = out + vout * CSout;
#pragma unroll
        for (int c8 = 0; c8 < OC; c8 += 8) st8(op + c8, &acc[c8]);
        // per-class stats into per-wave LDS accumulators
#pragma unroll
        for (int c = 0; c < OC; ++c) {
            float t = acc[c], t2 = acc[c] * acc[c];
            wred2(t, t2);
            if (lane == 0) { ps[w][2 * c] += t; ps[w][2 * c + 1] += t2; }
        }
    }
    __syncthreads();
    if (threadIdx.x < 48) {
        float v = ps[0][threadIdx.x] + ps[1][threadIdx.x] + ps[2][threadIdx.x]
                + ps[3][threadIdx.x];
        prt[(long)threadIdx.x * nrow + blockIdx.x] = v;
    }
}

// ---------------------------------------------------------------------------
// UNTILED channels-last conv (small layers: conv2, conv3), fused stats.
// ---------------------------------------------------------------------------
template <int IC, int OCT, int VX, int STRIDE>
__global__ __launch_bounds__(TPB) void conv_cl_k(
    const bf16* __restrict__ in, const float* __restrict__ wr,
    bf16* __restrict__ out,
    int ID, int IH, int IW, int OD, int OH, int OW,
    int CSin, int CSout, int OC, float* __restrict__ prt, int nrow)
{
    __shared__ float sw[27 * IC * OCT];
    __shared__ float ps[4][2 * OCT];
    const int cog0 = blockIdx.y * OCT;
    for (int i = threadIdx.x; i < 27 * IC * OCT; i += TPB) {
        int t_ci = i / OCT, c = i % OCT;
        sw[i] = wr[t_ci * OC + cog0 + c];
    }
    __syncthreads();

    const long S = (long)OD * OH * OW;
    long v[VX]; int xx[VX], yy[VX], zz[VX]; bool ok[VX];
    const long vb = (long)blockIdx.x * (TPB * VX) + threadIdx.x;
#pragma unroll
    for (int q = 0; q < VX; ++q) {
        v[q] = vb + (long)q * TPB;
        ok[q] = v[q] < S;
        long vv = ok[q] ? v[q] : 0;
        xx[q] = (int)(vv % OW); yy[q] = (int)((vv / OW) % OH);
        zz[q] = (int)(vv / ((long)OW * OH));
    }
    float acc[VX][OCT];
#pragma unroll
    for (int q = 0; q < VX; ++q)
#pragma unroll
        for (int c = 0; c < OCT; ++c) acc[q][c] = 0.f;

#pragma unroll 1
    for (int t = 0; t < 27; ++t) {
        const int kz = t / 9, ky = (t / 3) % 3, kx = t % 3;
        const float* swt = sw + t * IC * OCT;
        long bi[VX]; bool val[VX];
#pragma unroll
        for (int q = 0; q < VX; ++q) {
            int iz = zz[q] * STRIDE - 1 + kz;
            int iy = yy[q] * STRIDE - 1 + ky;
            int ix = xx[q] * STRIDE - 1 + kx;
            val[q] = ok[q] && (unsigned)iz < (unsigned)ID && (unsigned)iy < (unsigned)IH
                     && (unsigned)ix < (unsigned)IW;
            bi[q] = (((long)iz * IH + iy) * IW + ix) * CSin;
        }
#pragma unroll 1
        for (int c8 = 0; c8 < IC; c8 += 8) {
            float a[VX][8];
#pragma unroll
            for (int q = 0; q < VX; ++q) {
                if (val[q]) ld8(in + bi[q] + c8, a[q]); else zero8(a[q]);
            }
#pragma unroll
            for (int j = 0; j < 8; ++j) {
#pragma unroll
                for (int c4 = 0; c4 < OCT; c4 += 4) {
                    float4 wv = *(const float4*)&swt[(c8 + j) * OCT + c4];
#pragma unroll
                    for (int q = 0; q < VX; ++q) {
                        acc[q][c4 + 0] += a[q][j] * wv.x;
                        acc[q][c4 + 1] += a[q][j] * wv.y;
                        acc[q][c4 + 2] += a[q][j] * wv.z;
                        acc[q][c4 + 3] += a[q][j] * wv.w;
                    }
                }
            }
        }
    }
#pragma unroll
    for (int q = 0; q < VX; ++q) {
        if (!ok[q]) continue;
        bf16* op = out + v[q] * CSout + cog0;
#pragma unroll
        for (int c8 = 0; c8 < OCT; c8 += 8) st8(op + c8, &acc[q][c8]);
    }
    const int w = threadIdx.x >> 6, lane = threadIdx.x & 63;
#pragma unroll
    for (int c = 0; c < OCT; ++c) {
        float t = 0.f, t2 = 0.f;
#pragma unroll
        for (int q = 0; q < VX; ++q) { t += acc[q][c]; t2 += acc[q][c] * acc[q][c]; }
        wred2(t, t2);
        if (lane == 0) { ps[w][2 * c] = t; ps[w][2 * c + 1] = t2; }
    }
    __syncthreads();
    if (threadIdx.x < 2 * OCT) {
        float vv = ps[0][threadIdx.x] + ps[1][threadIdx.x] + ps[2][threadIdx.x]
                 + ps[3][threadIdx.x];
        prt[(long)(cog0 * 2 + threadIdx.x) * nrow + blockIdx.x] = vv;
    }
}

// ---------------------------------------------------------------------------
// UNTILED transposed conv (tconv3, tconv2 — L2/L3-resident inputs), fused stats.
// partial row = blockIdx.z * gridDim.x + blockIdx.x
// ---------------------------------------------------------------------------
template <int IC, int OCT, int VX>
__global__ __launch_bounds__(TPB) void tconv_cl_k(
    const bf16* __restrict__ in, const float* __restrict__ wr,
    bf16* __restrict__ out,
    int ID, int IH, int IW, int CSin, int CSout, int OC,
    float* __restrict__ prt, int nrow)
{
    const int cls = blockIdx.z;
    const int pz = (cls >> 2) & 1, py = (cls >> 1) & 1, px = cls & 1;
    const int nz = 1 + pz, ny = 1 + py, nx = 1 + px;
    const int ntap = nz * ny * nx;

    __shared__ float sw[8 * IC * OCT];
    __shared__ float ps[4][2 * OCT];
    const int cog0 = blockIdx.y * OCT;
    for (int i = threadIdx.x; i < ntap * IC * OCT; i += TPB) {
        int s = i / (IC * OCT);
        int rem = i % (IC * OCT);
        int ci = rem / OCT, c = rem % OCT;
        int a = s / (ny * nx), b = (s / nx) % ny, cc = s % nx;
        int kz = pz ? (a ? 2 : 0) : 1;
        int ky = py ? (b ? 2 : 0) : 1;
        int kx = px ? (cc ? 2 : 0) : 1;
        sw[i] = wr[((kz * 9 + ky * 3 + kx) * IC + ci) * OC + cog0 + c];
    }
    __syncthreads();

    const int OH = 2 * IH, OW = 2 * IW;
    const long SUB = (long)ID * IH * IW;
    long vi[VX]; int xi[VX], yi[VX], zi[VX]; bool ok[VX];
    const long vb = (long)blockIdx.x * (TPB * VX) + threadIdx.x;
#pragma unroll
    for (int q = 0; q < VX; ++q) {
        vi[q] = vb + (long)q * TPB;
        ok[q] = vi[q] < SUB;
        long vv = ok[q] ? vi[q] : 0;
        xi[q] = (int)(vv % IW); yi[q] = (int)((vv / IW) % IH);
        zi[q] = (int)(vv / ((long)IW * IH));
    }
    float acc[VX][OCT];
#pragma unroll
    for (int q = 0; q < VX; ++q)
#pragma unroll
        for (int c = 0; c < OCT; ++c) acc[q][c] = 0.f;

#pragma unroll 1
    for (int s = 0; s < ntap; ++s) {
        int a = s / (ny * nx), b = (s / nx) % ny, cc = s % nx;
        int dz = pz ? a : 0, dy = py ? b : 0, dx = px ? cc : 0;
        const float* swt = sw + s * IC * OCT;
        long bi[VX]; bool val[VX];
#pragma unroll
        for (int q = 0; q < VX; ++q) {
            int iz = zi[q] + dz, iy = yi[q] + dy, ix = xi[q] + dx;
            val[q] = ok[q] && iz < ID && iy < IH && ix < IW;
            bi[q] = (((long)iz * IH + iy) * IW + ix) * CSin;
        }
#pragma unroll 1
        for (int c8 = 0; c8 < IC; c8 += 8) {
            float a8[VX][8];
#pragma unroll
            for (int q = 0; q < VX; ++q) {
                if (val[q]) ld8(in + bi[q] + c8, a8[q]); else zero8(a8[q]);
            }
#pragma unroll
            for (int j = 0; j < 8; ++j)
#pragma unroll
                for (int c4 = 0; c4 < OCT; c4 += 4) {
                    float4 wv = *(const float4*)&swt[(c8 + j) * OCT + c4];
#pragma unroll
                    for (int q = 0; q < VX; ++q) {
                        acc[q][c4 + 0] += a8[q][j] * wv.x;
                        acc[q][c4 + 1] += a8[q][j] * wv.y;
                        acc[q][c4 + 2] += a8[q][j] * wv.z;
                        acc[q][c4 + 3] += a8[q][j] * wv.w;
                    }
                }
        }
    }
#pragma unroll
    for (int q = 0; q < VX; ++q) {
        if (!ok[q]) continue;
        int z = 2 * zi[q] + pz, y = 2 * yi[q] + py, x = 2 * xi[q] + px;
        long vout = ((long)z * OH + y) * OW + x;
        bf16* op = out + vout * CSout + cog0;
#pragma unroll
        for (int c8 = 0; c8 < OCT; c8 += 8) st8(op + c8, &acc[q][c8]);
    }
    const int w = threadIdx.x >> 6, lane = threadIdx.x & 63;
#pragma unroll
    for (int c = 0; c < OCT; ++c) {
        float t = 0.f, t2 = 0.f;
#pragma unroll
        for (int q = 0; q < VX; ++q) { t += acc[q][c]; t2 += acc[q][c] * acc[q][c]; }
        wred2(t, t2);
        if (lane == 0) { ps[w][2 * c] = t; ps[w][2 * c + 1] = t2; }
    }
    __syncthreads();
    if (threadIdx.x < 2 * OCT) {
        float vv = ps[0][threadIdx.x] + ps[1][threadIdx.x] + ps[2][threadIdx.x]
                 + ps[3][threadIdx.x];
        int row = blockIdx.z * gridDim.x + blockIdx.x;
        prt[(long)(cog0 * 2 + threadIdx.x) * nrow + row] = vv;
    }
}

// ---------------------------------------------------------------------------
// In-place BN+ReLU on channels-last bf16. CG=8, 4-way ILP across quarters.
// ---------------------------------------------------------------------------
__global__ __launch_bounds__(TPB) void bnrelu_cl_k(
    bf16* __restrict__ buf, long spatial, int CS,
    const float* __restrict__ stats, const float* __restrict__ g,
    const float* __restrict__ b, float invN)
{
    const int g0 = blockIdx.y * 8;
    float sc[8], sh[8];
#pragma unroll
    for (int c = 0; c < 8; ++c) {
        float mean = stats[2 * (g0 + c)] * invN;
        float var  = stats[2 * (g0 + c) + 1] * invN - mean * mean;
        sc[c] = rsqrtf(var + 1e-5f) * g[g0 + c];
        sh[c] = b[g0 + c] - mean * sc[c];
    }
    const long Q = spatial >> 2;
    for (long v = (long)blockIdx.x * TPB + threadIdx.x; v < Q;
         v += (long)gridDim.x * TPB) {
        bf16* p0 = buf + v * CS + g0;
        bf16* p1 = buf + (v + Q) * CS + g0;
        bf16* p2 = buf + (v + 2 * Q) * CS + g0;
        bf16* p3 = buf + (v + 3 * Q) * CS + g0;
        float a0[8], a1[8], a2[8], a3[8];
        ld8(p0, a0); ld8(p1, a1); ld8(p2, a2); ld8(p3, a3);
#pragma unroll
        for (int c = 0; c < 8; ++c) {
            float t0 = a0[c] * sc[c] + sh[c]; a0[c] = t0 > 0.f ? t0 : 0.f;
            float t1 = a1[c] * sc[c] + sh[c]; a1[c] = t1 > 0.f ? t1 : 0.f;
            float t2 = a2[c] * sc[c] + sh[c]; a2[c] = t2 > 0.f ? t2 : 0.f;
            float t3 = a3[c] * sc[c] + sh[c]; a3[c] = t3 > 0.f ? t3 : 0.f;
        }
        st8(p0, a0); st8(p1, a1); st8(p2, a2); st8(p3, a3);
    }
}

static inline int nblocks(long n, int per) { return (int)((n + per - 1) / per); }

extern "C" void kernel_launch(void* const* d_in, const int* in_sizes, int n_in,
                              void* d_out, int out_size, void* d_ws, size_t ws_size,
                              hipStream_t stream)
{
    const float* x    = (const float*)d_in[0];
    const float* w0   = (const float*)d_in[1];
    const float* g0   = (const float*)d_in[2];
    const float* b0   = (const float*)d_in[3];
    const float* w1   = (const float*)d_in[4];
    const float* g1   = (const float*)d_in[5];
    const float* b1   = (const float*)d_in[6];
    const float* w2   = (const float*)d_in[7];
    const float* g2   = (const float*)d_in[8];
    const float* b2   = (const float*)d_in[9];
    const float* w3   = (const float*)d_in[10];
    const float* g3   = (const float*)d_in[11];
    const float* b3   = (const float*)d_in[12];
    const float* wt3  = (const float*)d_in[13];
    const float* gt3  = (const float*)d_in[14];
    const float* bt3  = (const float*)d_in[15];
    const float* wt2  = (const float*)d_in[16];
    const float* gt2  = (const float*)d_in[17];
    const float* bt2  = (const float*)d_in[18];
    const float* wt1  = (const float*)d_in[19];
    const float* gt1  = (const float*)d_in[20];
    const float* bt1  = (const float*)d_in[21];
    const float* wout = (const float*)d_in[22];

    const long S128 = 128L * 128 * 128;
    const long S64  = 64L * 64 * 64;
    const long S32  = 32L * 32 * 32;
    const long S16  = 16L * 16 * 16;

    // ---- workspace (identical layout to passing rounds) ----
    float* stats = (float*)d_ws;             // 512 floats (cumulative offsets)
    float* wro   = stats + 512;              // 1728 floats (out-conv weights)
    bf16* base = (bf16*)((char*)d_ws + (512 + 1728) * 4);
    bf16* cat1 = base;                 // [128^3][32]: ch0-23 tconv1, ch24-31 s1
    bf16* cat2 = cat1 + S128 * 32;     // [64^3][48] : ch0-31 tconv2, ch32-47 s2
    bf16* cat3 = cat2 + S64 * 48;      // [32^3][64] : ch0-31 tconv3, ch32-63 s4
    bf16* s8   = cat3 + S32 * 64;      // [16^3][64]
    bf16* s1 = cat1 + 24;
    bf16* s2 = cat2 + 32;
    bf16* s4 = cat3 + 32;

    // repacked weights + stats partials live in d_out (consumed before final conv)
    float* wrd  = (float*)d_out;
    float* wr0  = wrd;            // 1728
    float* wr1  = wrd + 1728;     // 3456
    float* wr2  = wrd + 5184;     // 13824
    float* wr3  = wrd + 19008;    // 55296
    float* wrt3 = wrd + 74304;    // 55296
    float* wrt2 = wrd + 129600;   // 55296
    float* wrt1 = wrd + 184896;   // 31104 (end 216000 floats = 864 KB)
    float* prt  = wrd + 524288;   // partials, col-major, max 8192*48 floats

    repack_w_k<<<nblocks(1728, TPB),  TPB, 0, stream>>>(w0,  wr0,  8, 8);
    repack_w_k<<<nblocks(3456, TPB),  TPB, 0, stream>>>(w1,  wr1,  16, 8);
    repack_w_k<<<nblocks(13824, TPB), TPB, 0, stream>>>(w2,  wr2,  32, 16);
    repack_w_k<<<nblocks(55296, TPB), TPB, 0, stream>>>(w3,  wr3,  64, 32);
    repack_w_k<<<nblocks(55296, TPB), TPB, 0, stream>>>(wt3, wrt3, 32, 64);
    repack_w_k<<<nblocks(55296, TPB), TPB, 0, stream>>>(wt2, wrt2, 32, 64);
    repack_w_k<<<nblocks(31104, TPB), TPB, 0, stream>>>(wt1, wrt1, 24, 48);
    repack_w_k<<<nblocks(1728, TPB),  TPB, 0, stream>>>(wout, wro, 2, 32);

    // ---- encoder ----
    // conv0: x fp32 [8][128^3] -> s1. 4096 tiles of 8^3.
    conv0_tile_k<8, 8, 8><<<4096, TPB, 0, stream>>>(x, wr0, s1, 32, prt, 4096);
    sumcol_k<<<16, 64, 0, stream>>>(prt, 4096, stats + 0);
    bnrelu_cl_k<<<dim3(2048, 1), TPB, 0, stream>>>(s1, S128, 32, stats + 0, g0, b0, 1.f / S128);

    // conv1: s1 (IC=8) -> s2 (OC=16), stride2 128->64. 1024 tiles 4x8x8.
    conv_tile_k<8, 16, 2, 4, 8, 8, false, true><<<1024, TPB, 0, stream>>>(
        s1, wr1, s2, nullptr, 128, 128, 128, 64, 64, 64, 32, 48, prt, 1024);
    sumcol_k<<<32, 64, 0, stream>>>(prt, 1024, stats + 16);
    bnrelu_cl_k<<<dim3(256, 2), TPB, 0, stream>>>(s2, S64, 48, stats + 16, g1, b1, 1.f / S64);

    // conv2 (untiled): s2 (IC=16) -> s4 (OC=32), stride2 64->32
    conv_cl_k<16, 16, 2, 2><<<dim3(64, 2), TPB, 0, stream>>>(
        s2, wr2, s4, 64, 64, 64, 32, 32, 32, 48, 64, 32, prt, 64);
    sumcol_k<<<64, 64, 0, stream>>>(prt, 64, stats + 48);
    bnrelu_cl_k<<<dim3(32, 4), TPB, 0, stream>>>(s4, S32, 64, stats + 48, g2, b2, 1.f / S32);

    // conv3 (untiled): s4 (IC=32) -> s8 (OC=64), stride2 32->16
    conv_cl_k<32, 8, 1, 2><<<dim3(16, 8), TPB, 0, stream>>>(
        s4, wr3, s8, 32, 32, 32, 16, 16, 16, 64, 64, 64, prt, 16);
    sumcol_k<<<128, 64, 0, stream>>>(prt, 16, stats + 112);
    bnrelu_cl_k<<<dim3(4, 8), TPB, 0, stream>>>(s8, S16, 64, stats + 112, g3, b3, 1.f / S16);

    // ---- decoder ----
    // tconv3 (untiled): s8 (IC=64) -> cat3 ch0-31 (OC=32), 16->32
    tconv_cl_k<64, 16, 1><<<dim3(16, 2, 8), TPB, 0, stream>>>(
        s8, wrt3, cat3, 16, 16, 16, 64, 64, 32, prt, 128);
    sumcol_k<<<64, 64, 0, stream>>>(prt, 128, stats + 240);
    bnrelu_cl_k<<<dim3(32, 4), TPB, 0, stream>>>(cat3, S32, 64, stats + 240, gt3, bt3, 1.f / S32);

    // tconv2 (untiled): cat3 (IC=64) -> cat2 ch0-31 (OC=32), 32->64
    tconv_cl_k<64, 16, 1><<<dim3(128, 2, 8), TPB, 0, stream>>>(
        cat3, wrt2, cat2, 32, 32, 32, 64, 48, 32, prt, 1024);
    sumcol_k<<<64, 64, 0, stream>>>(prt, 1024, stats + 304);
    bnrelu_cl_k<<<dim3(256, 4), TPB, 0, stream>>>(cat2, S64, 48, stats + 304, gt2, bt2, 1.f / S64);

    // tconv1 tiled: cat2 (IC=48) -> cat1 ch0-23 (OC=24), 64->128. 1024 tiles.
    tconv1_tile_k<<<1024, TPB, 0, stream>>>(cat2, wrt1, cat1, 64, 64, 64, 48, 32, prt, 1024);
    sumcol_k<<<48, 64, 0, stream>>>(prt, 1024, stats + 368);
    bnrelu_cl_k<<<dim3(2048, 3), TPB, 0, stream>>>(cat1, S128, 32, stats + 368, gt1, bt1, 1.f / S128);

    // out conv tiled: cat1 (IC=32) -> d_out fp32 [2][128^3]. 8192 tiles 4x8x8.
    conv_tile_k<32, 2, 1, 4, 8, 8, true, false><<<8192, TPB, 0, stream>>>(
        cat1, wro, nullptr, (float*)d_out, 128, 128, 128, 128, 128, 128, 32, 0,
        nullptr, 0);
}

// Round 7
// 1109.871 us; speedup vs baseline: 9.9785x; 1.3956x over previous
//
#include <hip/hip_runtime.h>
#include <hip/hip_bf16.h>

typedef __hip_bfloat16 bf16;
#define TPB 256

typedef __attribute__((ext_vector_type(8))) short s8v;
typedef __attribute__((ext_vector_type(4))) float f4v;

// ---- bf16x8 vector helpers (16B) ----
__device__ inline void ld8(const bf16* p, float* v) {
    uint4 u = *(const uint4*)p;
    const unsigned short* s = (const unsigned short*)&u;
#pragma unroll
    for (int j = 0; j < 8; ++j) v[j] = __uint_as_float((unsigned)s[j] << 16);
}
__device__ inline void zero8(float* v) {
#pragma unroll
    for (int j = 0; j < 8; ++j) v[j] = 0.f;
}
__device__ inline void st8(bf16* p, const float* v) {
    bf16 t[8];
#pragma unroll
    for (int j = 0; j < 8; ++j) t[j] = __float2bfloat16(v[j]);
    *(uint4*)p = *(const uint4*)t;
}
__device__ inline void wred2(float& a, float& b) {
#pragma unroll
    for (int o = 32; o > 0; o >>= 1) {
        a += __shfl_down(a, o, 64);
        b += __shfl_down(b, o, 64);
    }
}

// ---------------------------------------------------------------------------
// Weight repack: w [OC][IC][27] -> wr [27][IC][OC]  (fp32)
// ---------------------------------------------------------------------------
__global__ __launch_bounds__(TPB) void repack_w_k(
    const float* __restrict__ w, float* __restrict__ wr, int OC, int IC)
{
    int idx = blockIdx.x * TPB + threadIdx.x;
    int n = OC * IC * 27;
    if (idx >= n) return;
    int co = idx / (IC * 27);
    int ci = (idx / 27) % IC;
    int t  = idx % 27;
    wr[(t * IC + ci) * OC + co] = w[idx];
}

// ---------------------------------------------------------------------------
// MFMA B-fragment weight repack: w [OCR][IC][27] fp32 ->
// wb [27][KC][NT][lane 64][j 8] bf16, zero-padded to K=KC*32, N=NT*16.
// lane holds B[k = kc*32 + (lane>>4)*8 + j][n = nt*16 + (lane&15)].
// ---------------------------------------------------------------------------
__global__ __launch_bounds__(TPB) void repack_wb_k(
    const float* __restrict__ w, bf16* __restrict__ wb,
    int OCR, int IC, int KC, int NT)
{
    int idx = blockIdx.x * TPB + threadIdx.x;
    int tot = 27 * KC * NT * 512;
    if (idx >= tot) return;
    int j = idx & 7;
    int l = (idx >> 3) & 63;
    int rest = idx >> 9;
    int nt = rest % NT;
    int kc = (rest / NT) % KC;
    int kt = rest / (NT * KC);
    int n = nt * 16 + (l & 15);
    int k = kc * 32 + (l >> 4) * 8 + j;
    float v = (n < OCR && k < IC) ? w[(n * IC + k) * 27 + kt] : 0.f;
    wb[idx] = __float2bfloat16(v);
}

// ---------------------------------------------------------------------------
// sumcol: fold column-major partials [col][nrow] -> stats[col]. 1 block/col.
// ---------------------------------------------------------------------------
__global__ __launch_bounds__(64) void sumcol_k(
    const float* __restrict__ p, int nrow, float* __restrict__ out)
{
    const long col = blockIdx.x;
    float s = 0.f;
    for (int r = threadIdx.x; r < nrow; r += 64) s += p[col * nrow + r];
    float d = 0.f;
    wred2(s, d);
    if (threadIdx.x == 0) out[col] = s;
}

// ---------------------------------------------------------------------------
// MFMA transposed conv, stride 2, k=3, channels-last. Tile 4x4x8 input
// voxels (+1 halo) staged in LDS (pitch 72, K zero-padded). 8 parity classes
// looped in-register, no barriers in main loop. 16x16x32 bf16 MFMA:
// M=16 voxels, N=16 out-channels, K=32 in-channels. Fused BN stats.
// ---------------------------------------------------------------------------
template <int IC, int OCR>
__global__ __launch_bounds__(TPB) void tconv_mfma_k(
    const bf16* __restrict__ in, const bf16* __restrict__ wb,
    bf16* __restrict__ out, int ID, int IH, int IW, int CSin, int CSout,
    float* __restrict__ prt, int nrow)
{
    constexpr int KC = (IC + 31) / 32;    // 2
    constexpr int NT = (OCR + 15) / 16;   // 2
    constexpr int TZ = 4, TY = 4, TX = 8;
    constexpr int EZ = TZ + 1, EY = TY + 1, EX = TX + 1;  // 5,5,9
    constexpr int NR = EZ * EY * EX;                      // 225
    constexpr int PITCH = 72;
    constexpr int CHKS = 9;               // staged 8-ch chunks (incl zero pad)
    constexpr int CHK = IC / 8;
    __shared__ __align__(16) bf16 si[NR * PITCH];         // 32.4 KB
    __shared__ float ps[4][64];
    const int ntx = IW / TX, nty = IH / TY;
    const int bx = blockIdx.x % ntx;
    const int by = (blockIdx.x / ntx) % nty;
    const int bz = blockIdx.x / (ntx * nty);
    const int x0 = bx * TX, y0 = by * TY, z0 = bz * TZ;
    for (int i = threadIdx.x; i < NR * CHKS; i += TPB) {
        int r = i / CHKS, c = i % CHKS;
        int rx = r % EX, ry = (r / EX) % EY, rz = r / (EX * EY);
        int gz = z0 + rz, gy = y0 + ry, gx = x0 + rx;
        uint4 u = make_uint4(0u, 0u, 0u, 0u);
        if (c < CHK && gz < ID && gy < IH && gx < IW)
            u = *(const uint4*)(in + (((long)gz * IH + gy) * IW + gx) * CSin + c * 8);
        *(uint4*)(si + r * PITCH + c * 8) = u;
    }
    __syncthreads();
    const int w = threadIdx.x >> 6;       // wave = z-slice
    const int lane = threadIdx.x & 63;
    const int q = lane >> 4, m = lane & 15;
    const int vy = m >> 3, vx = m & 7;
    const int OH = 2 * IH, OW = 2 * IW;
    float ls[NT], ls2[NT];
#pragma unroll
    for (int nt = 0; nt < NT; ++nt) { ls[nt] = 0.f; ls2[nt] = 0.f; }

#pragma unroll 1
    for (int cls = 0; cls < 8; ++cls) {
        const int pz = (cls >> 2) & 1, py = (cls >> 1) & 1, px = cls & 1;
        const int ny = 1 + py, nx = 1 + px;
        const int ntap = (1 + pz) * ny * nx;
        f4v acc[2][NT];
#pragma unroll
        for (int mt = 0; mt < 2; ++mt)
#pragma unroll
            for (int nt = 0; nt < NT; ++nt) acc[mt][nt] = (f4v)(0.f);
#pragma unroll 1
        for (int s = 0; s < ntap; ++s) {
            int a = s / (ny * nx), b = (s / nx) % ny, cc = s % nx;
            int dz = pz ? a : 0, dy = py ? b : 0, dx = px ? cc : 0;
            int kz = pz ? (a ? 2 : 0) : 1;
            int ky = py ? (b ? 2 : 0) : 1;
            int kx = px ? (cc ? 2 : 0) : 1;
            int kt = kz * 9 + ky * 3 + kx;
#pragma unroll
            for (int kc = 0; kc < KC; ++kc) {
                const bf16* bp = wb + (long)((kt * KC + kc) * NT) * 512 + lane * 8;
                s8v b0 = *(const s8v*)bp;
                s8v b1 = *(const s8v*)(bp + 512);
#pragma unroll
                for (int mt = 0; mt < 2; ++mt) {
                    int row = ((w + dz) * EY + (2 * mt + vy + dy)) * EX + (vx + dx);
                    s8v av = *(const s8v*)(si + row * PITCH + kc * 32 + q * 8);
                    acc[mt][0] = __builtin_amdgcn_mfma_f32_16x16x32_bf16(
                        av, b0, acc[mt][0], 0, 0, 0);
                    acc[mt][1] = __builtin_amdgcn_mfma_f32_16x16x32_bf16(
                        av, b1, acc[mt][1], 0, 0, 0);
                }
            }
        }
        // epilogue: store + stats
        const int z = 2 * (z0 + w) + pz;
#pragma unroll
        for (int mt = 0; mt < 2; ++mt)
#pragma unroll
            for (int nt = 0; nt < NT; ++nt) {
                const int n_ch = nt * 16 + m;
#pragma unroll
                for (int r = 0; r < 4; ++r) {
                    float v = acc[mt][nt][r];
                    ls[nt] += v; ls2[nt] += v * v;
                }
                if (n_ch < OCR) {
#pragma unroll
                    for (int r = 0; r < 4; ++r) {
                        int vrow = 4 * q + r;
                        int yy = 2 * (y0 + 2 * mt + (vrow >> 3)) + py;
                        int xx = 2 * (x0 + (vrow & 7)) + px;
                        out[(((long)z * OH + yy) * OW + xx) * CSout + n_ch] =
                            __float2bfloat16(acc[mt][nt][r]);
                    }
                }
            }
    }
    // fold stats: sum across quads -> lanes 0-15 hold per-channel sums
#pragma unroll
    for (int nt = 0; nt < NT; ++nt) {
        float t = ls[nt], t2 = ls2[nt];
        t  += __shfl_down(t, 32, 64);  t  += __shfl_down(t, 16, 64);
        t2 += __shfl_down(t2, 32, 64); t2 += __shfl_down(t2, 16, 64);
        if (lane < 16) {
            ps[w][2 * (nt * 16 + lane)]     = t;
            ps[w][2 * (nt * 16 + lane) + 1] = t2;
        }
    }
    __syncthreads();
    if (threadIdx.x < 2 * OCR) {
        float v = ps[0][threadIdx.x] + ps[1][threadIdx.x] + ps[2][threadIdx.x]
                + ps[3][threadIdx.x];
        prt[(long)threadIdx.x * nrow + blockIdx.x] = v;
    }
}

// ---------------------------------------------------------------------------
// conv0 tiled: fp32 NCDHW input [8][128^3], stride 1, LDS tile, fused stats.
// ---------------------------------------------------------------------------
template <int TZ, int TY, int TX>
__global__ __launch_bounds__(TPB) void conv0_tile_k(
    const float* __restrict__ x, const float* __restrict__ wr,
    bf16* __restrict__ out, int CSout, float* __restrict__ prt, int nrow)
{
    const int D = 128;
    const long S = (long)D * D * D;
    constexpr int EZ = TZ + 2, EY = TY + 2, EX = TX + 2;
    constexpr int NR = EZ * EY * EX;
    __shared__ __align__(16) bf16 si[NR * 8];
    __shared__ float sw[27 * 64];
    __shared__ float ps[4][16];
    const int ntx = D / TX, nty = D / TY;
    const int bx = blockIdx.x % ntx;
    const int by = (blockIdx.x / ntx) % nty;
    const int bz = blockIdx.x / (ntx * nty);
    const int x0 = bx * TX - 1, y0 = by * TY - 1, z0 = bz * TZ - 1;
    for (int i = threadIdx.x; i < 27 * 64; i += TPB) sw[i] = wr[i];
    for (int i = threadIdx.x; i < NR * 8; i += TPB) {
        int c = i / NR, r = i % NR;
        int rx = r % EX, ry = (r / EX) % EY, rz = r / (EX * EY);
        int gz = z0 + rz, gy = y0 + ry, gx = x0 + rx;
        float v = 0.f;
        if ((unsigned)gz < (unsigned)D && (unsigned)gy < (unsigned)D &&
            (unsigned)gx < (unsigned)D)
            v = x[(long)c * S + ((long)gz * D + gy) * D + gx];
        si[r * 8 + c] = __float2bfloat16(v);
    }
    __syncthreads();
    constexpr int VX = (TZ * TY * TX) / TPB;
    float acc[VX][8];
#pragma unroll
    for (int q = 0; q < VX; ++q) zero8(acc[q]);
    int lx[VX], ly[VX], lz[VX];
#pragma unroll
    for (int q = 0; q < VX; ++q) {
        int l = threadIdx.x + q * TPB;
        lx[q] = l % TX; ly[q] = (l / TX) % TY; lz[q] = l / (TX * TY);
    }
#pragma unroll 1
    for (int t = 0; t < 27; ++t) {
        const int kz = t / 9, ky = (t / 3) % 3, kx = t % 3;
        const float* swt = sw + t * 64;
        float a[VX][8];
#pragma unroll
        for (int q = 0; q < VX; ++q) {
            int r = ((lz[q] + kz) * EY + (ly[q] + ky)) * EX + (lx[q] + kx);
            ld8(si + r * 8, a[q]);
        }
#pragma unroll
        for (int j = 0; j < 8; ++j)
#pragma unroll
            for (int c4 = 0; c4 < 8; c4 += 4) {
                float4 wv = *(const float4*)&swt[j * 8 + c4];
#pragma unroll
                for (int q = 0; q < VX; ++q) {
                    acc[q][c4 + 0] += a[q][j] * wv.x;
                    acc[q][c4 + 1] += a[q][j] * wv.y;
                    acc[q][c4 + 2] += a[q][j] * wv.z;
                    acc[q][c4 + 3] += a[q][j] * wv.w;
                }
            }
    }
#pragma unroll
    for (int q = 0; q < VX; ++q) {
        long vox = ((long)(bz * TZ + lz[q]) * D + (by * TY + ly[q])) * D
                   + (bx * TX + lx[q]);
        st8(out + vox * CSout, acc[q]);
    }
    const int w = threadIdx.x >> 6, lane = threadIdx.x & 63;
#pragma unroll
    for (int c = 0; c < 8; ++c) {
        float t = 0.f, t2 = 0.f;
#pragma unroll
        for (int q = 0; q < VX; ++q) { t += acc[q][c]; t2 += acc[q][c] * acc[q][c]; }
        wred2(t, t2);
        if (lane == 0) { ps[w][2 * c] = t; ps[w][2 * c + 1] = t2; }
    }
    __syncthreads();
    if (threadIdx.x < 16) {
        float v = ps[0][threadIdx.x] + ps[1][threadIdx.x] + ps[2][threadIdx.x]
                + ps[3][threadIdx.x];
        prt[(long)threadIdx.x * nrow + blockIdx.x] = v;
    }
}

// ---------------------------------------------------------------------------
// Tiled channels-last conv, k=3, pad 1, stride S, LDS-staged, fused stats.
// CFOUT=true -> fp32 channel-first output (no stats).
// ---------------------------------------------------------------------------
template <int IC, int OC, int S, int TZ, int TY, int TX, bool CFOUT, bool DOSTATS>
__global__ __launch_bounds__(TPB) void conv_tile_k(
    const bf16* __restrict__ in, const float* __restrict__ wr,
    bf16* __restrict__ out, float* __restrict__ outf,
    int ID, int IH, int IW, int OD, int OH, int OW, int CSin, int CSout,
    float* __restrict__ prt, int nrow)
{
    constexpr int EZ = S * TZ + 3 - S, EYv = S * TY + 3 - S, EXv = S * TX + 3 - S;
    constexpr int NR = EZ * EYv * EXv;
    constexpr int PITCH = (IC == 8) ? 8 : IC + 8;
    constexpr int CHK = IC / 8;
    __shared__ __align__(16) bf16 si[NR * PITCH];
    __shared__ float sw[27 * IC * OC];
    __shared__ float ps[4][2 * OC];
    const int ntx = OW / TX, nty = OH / TY;
    const int bx = blockIdx.x % ntx;
    const int by = (blockIdx.x / ntx) % nty;
    const int bz = blockIdx.x / (ntx * nty);
    const int x0 = bx * TX * S - 1, y0 = by * TY * S - 1, z0 = bz * TZ * S - 1;
    for (int i = threadIdx.x; i < 27 * IC * OC; i += TPB) sw[i] = wr[i];
    for (int i = threadIdx.x; i < NR * CHK; i += TPB) {
        int r = i / CHK, c = i % CHK;
        int rx = r % EXv, ry = (r / EXv) % EYv, rz = r / (EXv * EYv);
        int gz = z0 + rz, gy = y0 + ry, gx = x0 + rx;
        uint4 u = make_uint4(0u, 0u, 0u, 0u);
        if ((unsigned)gz < (unsigned)ID && (unsigned)gy < (unsigned)IH &&
            (unsigned)gx < (unsigned)IW)
            u = *(const uint4*)(in + (((long)gz * IH + gy) * IW + gx) * CSin + c * 8);
        *(uint4*)(si + r * PITCH + c * 8) = u;
    }
    __syncthreads();
    constexpr int VX = (TZ * TY * TX) / TPB;
    float acc[VX][OC];
#pragma unroll
    for (int q = 0; q < VX; ++q)
#pragma unroll
        for (int c = 0; c < OC; ++c) acc[q][c] = 0.f;
    int lx[VX], ly[VX], lz[VX];
#pragma unroll
    for (int q = 0; q < VX; ++q) {
        int l = threadIdx.x + q * TPB;
        lx[q] = l % TX; ly[q] = (l / TX) % TY; lz[q] = l / (TX * TY);
    }
#pragma unroll 1
    for (int t = 0; t < 27; ++t) {
        const int kz = t / 9, ky = (t / 3) % 3, kx = t % 3;
        const float* swt = sw + t * IC * OC;
        int ro[VX];
#pragma unroll
        for (int q = 0; q < VX; ++q)
            ro[q] = (((lz[q] * S + kz) * EYv + (ly[q] * S + ky)) * EXv
                     + (lx[q] * S + kx)) * PITCH;
#pragma unroll
        for (int c8 = 0; c8 < IC; c8 += 8) {
            float a[VX][8];
#pragma unroll
            for (int q = 0; q < VX; ++q) ld8(si + ro[q] + c8, a[q]);
#pragma unroll
            for (int j = 0; j < 8; ++j) {
                if constexpr (OC % 4 == 0) {
#pragma unroll
                    for (int c4 = 0; c4 < OC; c4 += 4) {
                        float4 wv = *(const float4*)&swt[(c8 + j) * OC + c4];
#pragma unroll
                        for (int q = 0; q < VX; ++q) {
                            acc[q][c4 + 0] += a[q][j] * wv.x;
                            acc[q][c4 + 1] += a[q][j] * wv.y;
                            acc[q][c4 + 2] += a[q][j] * wv.z;
                            acc[q][c4 + 3] += a[q][j] * wv.w;
                        }
                    }
                } else {
                    float2 wv = *(const float2*)&swt[(c8 + j) * OC];
#pragma unroll
                    for (int q = 0; q < VX; ++q) {
                        acc[q][0] += a[q][j] * wv.x;
                        acc[q][1] += a[q][j] * wv.y;
                    }
                }
            }
        }
    }
#pragma unroll
    for (int q = 0; q < VX; ++q) {
        long vox = ((long)(bz * TZ + lz[q]) * OH + (by * TY + ly[q])) * OW
                   + (bx * TX + lx[q]);
        if constexpr (CFOUT) {
            long Sout = (long)OD * OH * OW;
#pragma unroll
            for (int c = 0; c < OC; ++c) outf[(long)c * Sout + vox] = acc[q][c];
        } else {
            bf16* op = out + vox * CSout;
#pragma unroll
            for (int c8 = 0; c8 < OC; c8 += 8) st8(op + c8, &acc[q][c8]);
        }
    }
    if constexpr (DOSTATS) {
        const int w = threadIdx.x >> 6, lane = threadIdx.x & 63;
#pragma unroll
        for (int c = 0; c < OC; ++c) {
            float t = 0.f, t2 = 0.f;
#pragma unroll
            for (int q = 0; q < VX; ++q) { t += acc[q][c]; t2 += acc[q][c] * acc[q][c]; }
            wred2(t, t2);
            if (lane == 0) { ps[w][2 * c] = t; ps[w][2 * c + 1] = t2; }
        }
        __syncthreads();
        if (threadIdx.x < 2 * OC) {
            float v = ps[0][threadIdx.x] + ps[1][threadIdx.x] + ps[2][threadIdx.x]
                    + ps[3][threadIdx.x];
            prt[(long)threadIdx.x * nrow + blockIdx.x] = v;
        }
    }
}

// ---------------------------------------------------------------------------
// UNTILED channels-last conv (small layers: conv2, conv3), fused stats.
// ---------------------------------------------------------------------------
template <int IC, int OCT, int VX, int STRIDE>
__global__ __launch_bounds__(TPB) void conv_cl_k(
    const bf16* __restrict__ in, const float* __restrict__ wr,
    bf16* __restrict__ out,
    int ID, int IH, int IW, int OD, int OH, int OW,
    int CSin, int CSout, int OC, float* __restrict__ prt, int nrow)
{
    __shared__ float sw[27 * IC * OCT];
    __shared__ float ps[4][2 * OCT];
    const int cog0 = blockIdx.y * OCT;
    for (int i = threadIdx.x; i < 27 * IC * OCT; i += TPB) {
        int t_ci = i / OCT, c = i % OCT;
        sw[i] = wr[t_ci * OC + cog0 + c];
    }
    __syncthreads();

    const long S = (long)OD * OH * OW;
    long v[VX]; int xx[VX], yy[VX], zz[VX]; bool ok[VX];
    const long vb = (long)blockIdx.x * (TPB * VX) + threadIdx.x;
#pragma unroll
    for (int q = 0; q < VX; ++q) {
        v[q] = vb + (long)q * TPB;
        ok[q] = v[q] < S;
        long vv = ok[q] ? v[q] : 0;
        xx[q] = (int)(vv % OW); yy[q] = (int)((vv / OW) % OH);
        zz[q] = (int)(vv / ((long)OW * OH));
    }
    float acc[VX][OCT];
#pragma unroll
    for (int q = 0; q < VX; ++q)
#pragma unroll
        for (int c = 0; c < OCT; ++c) acc[q][c] = 0.f;

#pragma unroll 1
    for (int t = 0; t < 27; ++t) {
        const int kz = t / 9, ky = (t / 3) % 3, kx = t % 3;
        const float* swt = sw + t * IC * OCT;
        long bi[VX]; bool val[VX];
#pragma unroll
        for (int q = 0; q < VX; ++q) {
            int iz = zz[q] * STRIDE - 1 + kz;
            int iy = yy[q] * STRIDE - 1 + ky;
            int ix = xx[q] * STRIDE - 1 + kx;
            val[q] = ok[q] && (unsigned)iz < (unsigned)ID && (unsigned)iy < (unsigned)IH
                     && (unsigned)ix < (unsigned)IW;
            bi[q] = (((long)iz * IH + iy) * IW + ix) * CSin;
        }
#pragma unroll 1
        for (int c8 = 0; c8 < IC; c8 += 8) {
            float a[VX][8];
#pragma unroll
            for (int q = 0; q < VX; ++q) {
                if (val[q]) ld8(in + bi[q] + c8, a[q]); else zero8(a[q]);
            }
#pragma unroll
            for (int j = 0; j < 8; ++j) {
#pragma unroll
                for (int c4 = 0; c4 < OCT; c4 += 4) {
                    float4 wv = *(const float4*)&swt[(c8 + j) * OCT + c4];
#pragma unroll
                    for (int q = 0; q < VX; ++q) {
                        acc[q][c4 + 0] += a[q][j] * wv.x;
                        acc[q][c4 + 1] += a[q][j] * wv.y;
                        acc[q][c4 + 2] += a[q][j] * wv.z;
                        acc[q][c4 + 3] += a[q][j] * wv.w;
                    }
                }
            }
        }
    }
#pragma unroll
    for (int q = 0; q < VX; ++q) {
        if (!ok[q]) continue;
        bf16* op = out + v[q] * CSout + cog0;
#pragma unroll
        for (int c8 = 0; c8 < OCT; c8 += 8) st8(op + c8, &acc[q][c8]);
    }
    const int w = threadIdx.x >> 6, lane = threadIdx.x & 63;
#pragma unroll
    for (int c = 0; c < OCT; ++c) {
        float t = 0.f, t2 = 0.f;
#pragma unroll
        for (int q = 0; q < VX; ++q) { t += acc[q][c]; t2 += acc[q][c] * acc[q][c]; }
        wred2(t, t2);
        if (lane == 0) { ps[w][2 * c] = t; ps[w][2 * c + 1] = t2; }
    }
    __syncthreads();
    if (threadIdx.x < 2 * OCT) {
        float vv = ps[0][threadIdx.x] + ps[1][threadIdx.x] + ps[2][threadIdx.x]
                 + ps[3][threadIdx.x];
        prt[(long)(cog0 * 2 + threadIdx.x) * nrow + blockIdx.x] = vv;
    }
}

// ---------------------------------------------------------------------------
// UNTILED transposed conv (tconv3 only — tiny), fused stats.
// ---------------------------------------------------------------------------
template <int IC, int OCT, int VX>
__global__ __launch_bounds__(TPB) void tconv_cl_k(
    const bf16* __restrict__ in, const float* __restrict__ wr,
    bf16* __restrict__ out,
    int ID, int IH, int IW, int CSin, int CSout, int OC,
    float* __restrict__ prt, int nrow)
{
    const int cls = blockIdx.z;
    const int pz = (cls >> 2) & 1, py = (cls >> 1) & 1, px = cls & 1;
    const int nz = 1 + pz, ny = 1 + py, nx = 1 + px;
    const int ntap = nz * ny * nx;

    __shared__ float sw[8 * IC * OCT];
    __shared__ float ps[4][2 * OCT];
    const int cog0 = blockIdx.y * OCT;
    for (int i = threadIdx.x; i < ntap * IC * OCT; i += TPB) {
        int s = i / (IC * OCT);
        int rem = i % (IC * OCT);
        int ci = rem / OCT, c = rem % OCT;
        int a = s / (ny * nx), b = (s / nx) % ny, cc = s % nx;
        int kz = pz ? (a ? 2 : 0) : 1;
        int ky = py ? (b ? 2 : 0) : 1;
        int kx = px ? (cc ? 2 : 0) : 1;
        sw[i] = wr[((kz * 9 + ky * 3 + kx) * IC + ci) * OC + cog0 + c];
    }
    __syncthreads();

    const int OH = 2 * IH, OW = 2 * IW;
    const long SUB = (long)ID * IH * IW;
    long vi[VX]; int xi[VX], yi[VX], zi[VX]; bool ok[VX];
    const long vb = (long)blockIdx.x * (TPB * VX) + threadIdx.x;
#pragma unroll
    for (int q = 0; q < VX; ++q) {
        vi[q] = vb + (long)q * TPB;
        ok[q] = vi[q] < SUB;
        long vv = ok[q] ? vi[q] : 0;
        xi[q] = (int)(vv % IW); yi[q] = (int)((vv / IW) % IH);
        zi[q] = (int)(vv / ((long)IW * IH));
    }
    float acc[VX][OCT];
#pragma unroll
    for (int q = 0; q < VX; ++q)
#pragma unroll
        for (int c = 0; c < OCT; ++c) acc[q][c] = 0.f;

#pragma unroll 1
    for (int s = 0; s < ntap; ++s) {
        int a = s / (ny * nx), b = (s / nx) % ny, cc = s % nx;
        int dz = pz ? a : 0, dy = py ? b : 0, dx = px ? cc : 0;
        const float* swt = sw + s * IC * OCT;
        long bi[VX]; bool val[VX];
#pragma unroll
        for (int q = 0; q < VX; ++q) {
            int iz = zi[q] + dz, iy = yi[q] + dy, ix = xi[q] + dx;
            val[q] = ok[q] && iz < ID && iy < IH && ix < IW;
            bi[q] = (((long)iz * IH + iy) * IW + ix) * CSin;
        }
#pragma unroll 1
        for (int c8 = 0; c8 < IC; c8 += 8) {
            float a8[VX][8];
#pragma unroll
            for (int q = 0; q < VX; ++q) {
                if (val[q]) ld8(in + bi[q] + c8, a8[q]); else zero8(a8[q]);
            }
#pragma unroll
            for (int j = 0; j < 8; ++j)
#pragma unroll
                for (int c4 = 0; c4 < OCT; c4 += 4) {
                    float4 wv = *(const float4*)&swt[(c8 + j) * OCT + c4];
#pragma unroll
                    for (int q = 0; q < VX; ++q) {
                        acc[q][c4 + 0] += a8[q][j] * wv.x;
                        acc[q][c4 + 1] += a8[q][j] * wv.y;
                        acc[q][c4 + 2] += a8[q][j] * wv.z;
                        acc[q][c4 + 3] += a8[q][j] * wv.w;
                    }
                }
        }
    }
#pragma unroll
    for (int q = 0; q < VX; ++q) {
        if (!ok[q]) continue;
        int z = 2 * zi[q] + pz, y = 2 * yi[q] + py, x = 2 * xi[q] + px;
        long vout = ((long)z * OH + y) * OW + x;
        bf16* op = out + vout * CSout + cog0;
#pragma unroll
        for (int c8 = 0; c8 < OCT; c8 += 8) st8(op + c8, &acc[q][c8]);
    }
    const int w = threadIdx.x >> 6, lane = threadIdx.x & 63;
#pragma unroll
    for (int c = 0; c < OCT; ++c) {
        float t = 0.f, t2 = 0.f;
#pragma unroll
        for (int q = 0; q < VX; ++q) { t += acc[q][c]; t2 += acc[q][c] * acc[q][c]; }
        wred2(t, t2);
        if (lane == 0) { ps[w][2 * c] = t; ps[w][2 * c + 1] = t2; }
    }
    __syncthreads();
    if (threadIdx.x < 2 * OCT) {
        float vv = ps[0][threadIdx.x] + ps[1][threadIdx.x] + ps[2][threadIdx.x]
                 + ps[3][threadIdx.x];
        int row = blockIdx.z * gridDim.x + blockIdx.x;
        prt[(long)(cog0 * 2 + threadIdx.x) * nrow + row] = vv;
    }
}

// ---------------------------------------------------------------------------
// In-place BN+ReLU on channels-last bf16. CG=8, 4-way ILP across quarters.
// ---------------------------------------------------------------------------
__global__ __launch_bounds__(TPB) void bnrelu_cl_k(
    bf16* __restrict__ buf, long spatial, int CS,
    const float* __restrict__ stats, const float* __restrict__ g,
    const float* __restrict__ b, float invN)
{
    const int g0 = blockIdx.y * 8;
    float sc[8], sh[8];
#pragma unroll
    for (int c = 0; c < 8; ++c) {
        float mean = stats[2 * (g0 + c)] * invN;
        float var  = stats[2 * (g0 + c) + 1] * invN - mean * mean;
        sc[c] = rsqrtf(var + 1e-5f) * g[g0 + c];
        sh[c] = b[g0 + c] - mean * sc[c];
    }
    const long Q = spatial >> 2;
    for (long v = (long)blockIdx.x * TPB + threadIdx.x; v < Q;
         v += (long)gridDim.x * TPB) {
        bf16* p0 = buf + v * CS + g0;
        bf16* p1 = buf + (v + Q) * CS + g0;
        bf16* p2 = buf + (v + 2 * Q) * CS + g0;
        bf16* p3 = buf + (v + 3 * Q) * CS + g0;
        float a0[8], a1[8], a2[8], a3[8];
        ld8(p0, a0); ld8(p1, a1); ld8(p2, a2); ld8(p3, a3);
#pragma unroll
        for (int c = 0; c < 8; ++c) {
            float t0 = a0[c] * sc[c] + sh[c]; a0[c] = t0 > 0.f ? t0 : 0.f;
            float t1 = a1[c] * sc[c] + sh[c]; a1[c] = t1 > 0.f ? t1 : 0.f;
            float t2 = a2[c] * sc[c] + sh[c]; a2[c] = t2 > 0.f ? t2 : 0.f;
            float t3 = a3[c] * sc[c] + sh[c]; a3[c] = t3 > 0.f ? t3 : 0.f;
        }
        st8(p0, a0); st8(p1, a1); st8(p2, a2); st8(p3, a3);
    }
}

static inline int nblocks(long n, int per) { return (int)((n + per - 1) / per); }

extern "C" void kernel_launch(void* const* d_in, const int* in_sizes, int n_in,
                              void* d_out, int out_size, void* d_ws, size_t ws_size,
                              hipStream_t stream)
{
    const float* x    = (const float*)d_in[0];
    const float* w0   = (const float*)d_in[1];
    const float* g0   = (const float*)d_in[2];
    const float* b0   = (const float*)d_in[3];
    const float* w1   = (const float*)d_in[4];
    const float* g1   = (const float*)d_in[5];
    const float* b1   = (const float*)d_in[6];
    const float* w2   = (const float*)d_in[7];
    const float* g2   = (const float*)d_in[8];
    const float* b2   = (const float*)d_in[9];
    const float* w3   = (const float*)d_in[10];
    const float* g3   = (const float*)d_in[11];
    const float* b3   = (const float*)d_in[12];
    const float* wt3  = (const float*)d_in[13];
    const float* gt3  = (const float*)d_in[14];
    const float* bt3  = (const float*)d_in[15];
    const float* wt2  = (const float*)d_in[16];
    const float* gt2  = (const float*)d_in[17];
    const float* bt2  = (const float*)d_in[18];
    const float* wt1  = (const float*)d_in[19];
    const float* gt1  = (const float*)d_in[20];
    const float* bt1  = (const float*)d_in[21];
    const float* wout = (const float*)d_in[22];

    const long S128 = 128L * 128 * 128;
    const long S64  = 64L * 64 * 64;
    const long S32  = 32L * 32 * 32;
    const long S16  = 16L * 16 * 16;

    // ---- workspace (identical layout to passing rounds) ----
    float* stats = (float*)d_ws;
    float* wro   = stats + 512;
    bf16* base = (bf16*)((char*)d_ws + (512 + 1728) * 4);
    bf16* cat1 = base;                 // [128^3][32]: ch0-23 tconv1, ch24-31 s1
    bf16* cat2 = cat1 + S128 * 32;     // [64^3][48] : ch0-31 tconv2, ch32-47 s2
    bf16* cat3 = cat2 + S64 * 48;      // [32^3][64] : ch0-31 tconv3, ch32-63 s4
    bf16* s8   = cat3 + S32 * 64;      // [16^3][64]
    bf16* s1 = cat1 + 24;
    bf16* s2 = cat2 + 32;
    bf16* s4 = cat3 + 32;

    // repacked weights + stats partials live in d_out (consumed before final conv)
    float* wrd  = (float*)d_out;
    float* wr0  = wrd;            // 1728
    float* wr1  = wrd + 1728;     // 3456
    float* wr2  = wrd + 5184;     // 13824
    float* wr3  = wrd + 19008;    // 55296
    float* wrt3 = wrd + 74304;    // 55296 (ends 129600)
    bf16*  wbt1 = (bf16*)(wrd + 129600);  // 55296 bf16 = 27648 floats
    bf16*  wbt2 = (bf16*)(wrd + 157248);  // 55296 bf16 (ends 184896)
    float* prt  = wrd + 524288;   // partials, col-major

    repack_w_k<<<nblocks(1728, TPB),  TPB, 0, stream>>>(w0,  wr0,  8, 8);
    repack_w_k<<<nblocks(3456, TPB),  TPB, 0, stream>>>(w1,  wr1,  16, 8);
    repack_w_k<<<nblocks(13824, TPB), TPB, 0, stream>>>(w2,  wr2,  32, 16);
    repack_w_k<<<nblocks(55296, TPB), TPB, 0, stream>>>(w3,  wr3,  64, 32);
    repack_w_k<<<nblocks(55296, TPB), TPB, 0, stream>>>(wt3, wrt3, 32, 64);
    repack_wb_k<<<nblocks(55296, TPB), TPB, 0, stream>>>(wt1, wbt1, 24, 48, 2, 2);
    repack_wb_k<<<nblocks(55296, TPB), TPB, 0, stream>>>(wt2, wbt2, 32, 64, 2, 2);
    repack_w_k<<<nblocks(1728, TPB),  TPB, 0, stream>>>(wout, wro, 2, 32);

    // ---- encoder ----
    conv0_tile_k<8, 8, 8><<<4096, TPB, 0, stream>>>(x, wr0, s1, 32, prt, 4096);
    sumcol_k<<<16, 64, 0, stream>>>(prt, 4096, stats + 0);
    bnrelu_cl_k<<<dim3(2048, 1), TPB, 0, stream>>>(s1, S128, 32, stats + 0, g0, b0, 1.f / S128);

    conv_tile_k<8, 16, 2, 4, 8, 8, false, true><<<1024, TPB, 0, stream>>>(
        s1, wr1, s2, nullptr, 128, 128, 128, 64, 64, 64, 32, 48, prt, 1024);
    sumcol_k<<<32, 64, 0, stream>>>(prt, 1024, stats + 16);
    bnrelu_cl_k<<<dim3(256, 2), TPB, 0, stream>>>(s2, S64, 48, stats + 16, g1, b1, 1.f / S64);

    conv_cl_k<16, 16, 2, 2><<<dim3(64, 2), TPB, 0, stream>>>(
        s2, wr2, s4, 64, 64, 64, 32, 32, 32, 48, 64, 32, prt, 64);
    sumcol_k<<<64, 64, 0, stream>>>(prt, 64, stats + 48);
    bnrelu_cl_k<<<dim3(32, 4), TPB, 0, stream>>>(s4, S32, 64, stats + 48, g2, b2, 1.f / S32);

    conv_cl_k<32, 8, 1, 2><<<dim3(16, 8), TPB, 0, stream>>>(
        s4, wr3, s8, 32, 32, 32, 16, 16, 16, 64, 64, 64, prt, 16);
    sumcol_k<<<128, 64, 0, stream>>>(prt, 16, stats + 112);
    bnrelu_cl_k<<<dim3(4, 8), TPB, 0, stream>>>(s8, S16, 64, stats + 112, g3, b3, 1.f / S16);

    // ---- decoder ----
    // tconv3 (untiled vector): s8 (IC=64) -> cat3 ch0-31 (OC=32), 16->32
    tconv_cl_k<64, 16, 1><<<dim3(16, 2, 8), TPB, 0, stream>>>(
        s8, wrt3, cat3, 16, 16, 16, 64, 64, 32, prt, 128);
    sumcol_k<<<64, 64, 0, stream>>>(prt, 128, stats + 240);
    bnrelu_cl_k<<<dim3(32, 4), TPB, 0, stream>>>(cat3, S32, 64, stats + 240, gt3, bt3, 1.f / S32);

    // tconv2 MFMA: cat3 (IC=64) -> cat2 ch0-31 (OC=32), 32->64. 256 blocks.
    tconv_mfma_k<64, 32><<<256, TPB, 0, stream>>>(
        cat3, wbt2, cat2, 32, 32, 32, 64, 48, prt, 256);
    sumcol_k<<<64, 64, 0, stream>>>(prt, 256, stats + 304);
    bnrelu_cl_k<<<dim3(256, 4), TPB, 0, stream>>>(cat2, S64, 48, stats + 304, gt2, bt2, 1.f / S64);

    // tconv1 MFMA: cat2 (IC=48) -> cat1 ch0-23 (OC=24), 64->128. 2048 blocks.
    tconv_mfma_k<48, 24><<<2048, TPB, 0, stream>>>(
        cat2, wbt1, cat1, 64, 64, 64, 48, 32, prt, 2048);
    sumcol_k<<<48, 64, 0, stream>>>(prt, 2048, stats + 368);
    bnrelu_cl_k<<<dim3(2048, 3), TPB, 0, stream>>>(cat1, S128, 32, stats + 368, gt1, bt1, 1.f / S128);

    // out conv tiled: cat1 (IC=32) -> d_out fp32 [2][128^3]. 8192 tiles 4x8x8.
    conv_tile_k<32, 2, 1, 4, 8, 8, true, false><<<8192, TPB, 0, stream>>>(
        cat1, wro, nullptr, (float*)d_out, 128, 128, 128, 128, 128, 128, 32, 0,
        nullptr, 0);
}

// Round 8
// 765.944 us; speedup vs baseline: 14.4591x; 1.4490x over previous
//
#include <hip/hip_runtime.h>
#include <hip/hip_bf16.h>

typedef __hip_bfloat16 bf16;
#define TPB 256

typedef __attribute__((ext_vector_type(8))) short s8v;
typedef __attribute__((ext_vector_type(4))) float f4v;

// ---- bf16x8 vector helpers (16B) ----
__device__ inline void ld8(const bf16* p, float* v) {
    uint4 u = *(const uint4*)p;
    const unsigned short* s = (const unsigned short*)&u;
#pragma unroll
    for (int j = 0; j < 8; ++j) v[j] = __uint_as_float((unsigned)s[j] << 16);
}
__device__ inline void st8(bf16* p, const float* v) {
    bf16 t[8];
#pragma unroll
    for (int j = 0; j < 8; ++j) t[j] = __float2bfloat16(v[j]);
    *(uint4*)p = *(const uint4*)t;
}
__device__ inline void wred2(float& a, float& b) {
#pragma unroll
    for (int o = 32; o > 0; o >>= 1) {
        a += __shfl_down(a, o, 64);
        b += __shfl_down(b, o, 64);
    }
}

// ---------------------------------------------------------------------------
// B-fragment repack for MFMA convs: w [OCR][IC][27] fp32 ->
// wb [KK][NT][lane 64][j 8] bf16. k = kk*32 + (lane>>4)*8 + j encodes
// flat (tap, ci): tap = k/IC, ci = k%IC. Zero-padded for k >= 27*IC, n >= OCR.
// ---------------------------------------------------------------------------
__global__ __launch_bounds__(TPB) void repack_wbc_k(
    const float* __restrict__ w, bf16* __restrict__ wb,
    int OCR, int IC, int KK, int NT)
{
    int idx = blockIdx.x * TPB + threadIdx.x;
    int tot = KK * NT * 512;
    if (idx >= tot) return;
    int j = idx & 7;
    int l = (idx >> 3) & 63;
    int rest = idx >> 9;
    int nt = rest % NT;
    int kk = rest / NT;
    int n = nt * 16 + (l & 15);
    int k = kk * 32 + (l >> 4) * 8 + j;
    int tap = k / IC, ci = k % IC;
    float v = (n < OCR && tap < 27) ? w[(n * IC + ci) * 27 + tap] : 0.f;
    wb[idx] = __float2bfloat16(v);
}

// ---------------------------------------------------------------------------
// B-fragment repack for MFMA tconv (per-tap K): wb [27][KC][NT][lane][8].
// ---------------------------------------------------------------------------
__global__ __launch_bounds__(TPB) void repack_wb_k(
    const float* __restrict__ w, bf16* __restrict__ wb,
    int OCR, int IC, int KC, int NT)
{
    int idx = blockIdx.x * TPB + threadIdx.x;
    int tot = 27 * KC * NT * 512;
    if (idx >= tot) return;
    int j = idx & 7;
    int l = (idx >> 3) & 63;
    int rest = idx >> 9;
    int nt = rest % NT;
    int kc = (rest / NT) % KC;
    int kt = rest / (NT * KC);
    int n = nt * 16 + (l & 15);
    int k = kc * 32 + (l >> 4) * 8 + j;
    float v = (n < OCR && k < IC) ? w[(n * IC + k) * 27 + kt] : 0.f;
    wb[idx] = __float2bfloat16(v);
}

// ---------------------------------------------------------------------------
// sumcol: fold column-major partials [col][nrow] -> stats[col]. 1 block/col.
// ---------------------------------------------------------------------------
__global__ __launch_bounds__(64) void sumcol_k(
    const float* __restrict__ p, int nrow, float* __restrict__ out)
{
    const long col = blockIdx.x;
    float s = 0.f;
    for (int r = threadIdx.x; r < nrow; r += 64) s += p[col * nrow + r];
    float d = 0.f;
    wred2(s, d);
    if (threadIdx.x == 0) out[col] = s;
}

// ---------------------------------------------------------------------------
// Unified MFMA direct conv, k=3, pad 1, stride 1 or 2, channels-last.
// K-dim = flattened (tap, ci) padded to KK*32. Wave = z-slice (TZ must be 4).
// A: ds_read_b128 per lane from LDS-staged input tile.
// B: 1KB/wave coalesced global loads of pre-packed fragments.
// INF32: input is fp32 channel-first (conv0). CFOUT: fp32 CF output (no stats).
// ---------------------------------------------------------------------------
template <int IC, int OCR, int STRIDE, int TZ, int TY, int TX,
          bool INF32, bool CFOUT, bool DOSTATS>
__global__ __launch_bounds__(TPB) void conv_mfma_k(
    const void* __restrict__ in_, const bf16* __restrict__ wb,
    bf16* __restrict__ out, float* __restrict__ outf,
    int ID, int IH, int IW, int OD, int OH, int OW, int CSin, int CSout,
    float* __restrict__ prt, int nrow)
{
    constexpr int EZ = STRIDE * TZ + 3 - STRIDE;
    constexpr int EY = STRIDE * TY + 3 - STRIDE;
    constexpr int EX = STRIDE * TX + 3 - STRIDE;
    constexpr int NR = EZ * EY * EX;
    constexpr int PITCH = (IC == 8) ? 8 : IC + 8;
    constexpr int CHK = IC / 8;
    constexpr int KK = (27 * IC + 31) / 32;
    constexpr int NT = (OCR + 15) / 16;
    constexpr int MT = (TY * TX) / 16;
    constexpr int MROWS = 16 / TX;
    static_assert(TZ == 4, "wave = z-slice");
    __shared__ __align__(16) bf16 si[NR * PITCH];
    __shared__ float ps[4][2 * 16 * NT];
    const int ntx = OW / TX, nty = OH / TY;
    const int bx = blockIdx.x % ntx;
    const int by = (blockIdx.x / ntx) % nty;
    const int bz = blockIdx.x / (ntx * nty);
    const int x0 = bx * TX * STRIDE - 1;
    const int y0 = by * TY * STRIDE - 1;
    const int z0 = bz * TZ * STRIDE - 1;

    if constexpr (INF32) {
        const float* x = (const float*)in_;
        const long S = (long)ID * IH * IW;
        for (int i = threadIdx.x; i < NR * 8; i += TPB) {
            int c = i / NR, r = i % NR;
            int rx = r % EX, ry = (r / EX) % EY, rz = r / (EX * EY);
            int gz = z0 + rz, gy = y0 + ry, gx = x0 + rx;
            float v = 0.f;
            if ((unsigned)gz < (unsigned)ID && (unsigned)gy < (unsigned)IH &&
                (unsigned)gx < (unsigned)IW)
                v = x[(long)c * S + ((long)gz * IH + gy) * IW + gx];
            si[r * PITCH + c] = __float2bfloat16(v);
        }
    } else {
        const bf16* in = (const bf16*)in_;
        for (int i = threadIdx.x; i < NR * CHK; i += TPB) {
            int r = i / CHK, c = i % CHK;
            int rx = r % EX, ry = (r / EX) % EY, rz = r / (EX * EY);
            int gz = z0 + rz, gy = y0 + ry, gx = x0 + rx;
            uint4 u = make_uint4(0u, 0u, 0u, 0u);
            if ((unsigned)gz < (unsigned)ID && (unsigned)gy < (unsigned)IH &&
                (unsigned)gx < (unsigned)IW)
                u = *(const uint4*)(in + (((long)gz * IH + gy) * IW + gx) * CSin + c * 8);
            *(uint4*)(si + r * PITCH + c * 8) = u;
        }
    }
    __syncthreads();

    const int w = threadIdx.x >> 6;     // z-slice within tile
    const int lane = threadIdx.x & 63;
    const int q = lane >> 4, m = lane & 15;
    const int vy = m / TX, vx = m % TX;

    f4v acc[MT][NT];
#pragma unroll
    for (int mt = 0; mt < MT; ++mt)
#pragma unroll
        for (int nt = 0; nt < NT; ++nt) acc[mt][nt] = (f4v)(0.f);

#pragma unroll 1
    for (int kk = 0; kk < KK; ++kk) {
        int flat = kk * 32 + q * 8;
        int tb = flat / IC; if (tb > 26) tb = 26;
        const int cb = flat % IC;
        const int kz = tb / 9, ky = (tb / 3) % 3, kx = tb % 3;
        s8v bfr[NT];
#pragma unroll
        for (int nt = 0; nt < NT; ++nt)
            bfr[nt] = *(const s8v*)(wb + ((long)(kk * NT + nt) << 9) + lane * 8);
        const int iz = w * STRIDE + kz;
        const int ixc = vx * STRIDE + kx;
#pragma unroll
        for (int mt = 0; mt < MT; ++mt) {
            int iy = (mt * MROWS + vy) * STRIDE + ky;
            int row = (iz * EY + iy) * EX + ixc;
            s8v av = *(const s8v*)(si + row * PITCH + cb);
#pragma unroll
            for (int nt = 0; nt < NT; ++nt)
                acc[mt][nt] = __builtin_amdgcn_mfma_f32_16x16x32_bf16(
                    av, bfr[nt], acc[mt][nt], 0, 0, 0);
        }
    }

    // epilogue: store + stats
    float ls[NT], ls2[NT];
#pragma unroll
    for (int nt = 0; nt < NT; ++nt) { ls[nt] = 0.f; ls2[nt] = 0.f; }
    const int oz = bz * TZ + w;
#pragma unroll
    for (int mt = 0; mt < MT; ++mt)
#pragma unroll
        for (int nt = 0; nt < NT; ++nt) {
            const int n_ch = nt * 16 + m;
            if constexpr (DOSTATS) {
#pragma unroll
                for (int r = 0; r < 4; ++r) {
                    float v = acc[mt][nt][r];
                    ls[nt] += v; ls2[nt] += v * v;   // padded cols are exactly 0
                }
            }
            if (n_ch < OCR) {
#pragma unroll
                for (int r = 0; r < 4; ++r) {
                    int vrow = 4 * q + r;
                    int oy = by * TY + mt * MROWS + vrow / TX;
                    int ox = bx * TX + vrow % TX;
                    long vox = ((long)oz * OH + oy) * OW + ox;
                    if constexpr (CFOUT) {
                        long Sout = (long)OD * OH * OW;
                        outf[(long)n_ch * Sout + vox] = acc[mt][nt][r];
                    } else {
                        out[vox * CSout + n_ch] = __float2bfloat16(acc[mt][nt][r]);
                    }
                }
            }
        }
    if constexpr (DOSTATS) {
#pragma unroll
        for (int nt = 0; nt < NT; ++nt) {
            float t = ls[nt], t2 = ls2[nt];
            t  += __shfl_down(t, 32, 64);  t  += __shfl_down(t, 16, 64);
            t2 += __shfl_down(t2, 32, 64); t2 += __shfl_down(t2, 16, 64);
            if (lane < 16) {
                ps[w][2 * (nt * 16 + lane)]     = t;
                ps[w][2 * (nt * 16 + lane) + 1] = t2;
            }
        }
        __syncthreads();
        if (threadIdx.x < 2 * OCR) {
            float v = ps[0][threadIdx.x] + ps[1][threadIdx.x]
                    + ps[2][threadIdx.x] + ps[3][threadIdx.x];
            prt[(long)threadIdx.x * nrow + blockIdx.x] = v;
        }
    }
}

// ---------------------------------------------------------------------------
// MFMA transposed conv, stride 2, k=3 (verified r6/r7). Tile 4x4x8 input
// voxels (+1 halo) in LDS; 8 parity classes in-register; fused BN stats.
// ---------------------------------------------------------------------------
template <int IC, int OCR>
__global__ __launch_bounds__(TPB) void tconv_mfma_k(
    const bf16* __restrict__ in, const bf16* __restrict__ wb,
    bf16* __restrict__ out, int ID, int IH, int IW, int CSin, int CSout,
    float* __restrict__ prt, int nrow)
{
    constexpr int KC = (IC + 31) / 32;
    constexpr int NT = (OCR + 15) / 16;
    constexpr int TZ = 4, TY = 4, TX = 8;
    constexpr int EZ = TZ + 1, EY = TY + 1, EX = TX + 1;
    constexpr int NR = EZ * EY * EX;
    constexpr int PITCH = 72;
    constexpr int CHKS = 9;
    constexpr int CHK = IC / 8;
    __shared__ __align__(16) bf16 si[NR * PITCH];
    __shared__ float ps[4][64];
    const int ntx = IW / TX, nty = IH / TY;
    const int bx = blockIdx.x % ntx;
    const int by = (blockIdx.x / ntx) % nty;
    const int bz = blockIdx.x / (ntx * nty);
    const int x0 = bx * TX, y0 = by * TY, z0 = bz * TZ;
    for (int i = threadIdx.x; i < NR * CHKS; i += TPB) {
        int r = i / CHKS, c = i % CHKS;
        int rx = r % EX, ry = (r / EX) % EY, rz = r / (EX * EY);
        int gz = z0 + rz, gy = y0 + ry, gx = x0 + rx;
        uint4 u = make_uint4(0u, 0u, 0u, 0u);
        if (c < CHK && gz < ID && gy < IH && gx < IW)
            u = *(const uint4*)(in + (((long)gz * IH + gy) * IW + gx) * CSin + c * 8);
        *(uint4*)(si + r * PITCH + c * 8) = u;
    }
    __syncthreads();
    const int w = threadIdx.x >> 6;
    const int lane = threadIdx.x & 63;
    const int q = lane >> 4, m = lane & 15;
    const int vy = m >> 3, vx = m & 7;
    const int OH = 2 * IH, OW = 2 * IW;
    float ls[NT], ls2[NT];
#pragma unroll
    for (int nt = 0; nt < NT; ++nt) { ls[nt] = 0.f; ls2[nt] = 0.f; }

#pragma unroll 1
    for (int cls = 0; cls < 8; ++cls) {
        const int pz = (cls >> 2) & 1, py = (cls >> 1) & 1, px = cls & 1;
        const int ny = 1 + py, nx = 1 + px;
        const int ntap = (1 + pz) * ny * nx;
        f4v acc[2][NT];
#pragma unroll
        for (int mt = 0; mt < 2; ++mt)
#pragma unroll
            for (int nt = 0; nt < NT; ++nt) acc[mt][nt] = (f4v)(0.f);
#pragma unroll 1
        for (int s = 0; s < ntap; ++s) {
            int a = s / (ny * nx), b = (s / nx) % ny, cc = s % nx;
            int dz = pz ? a : 0, dy = py ? b : 0, dx = px ? cc : 0;
            int kz = pz ? (a ? 2 : 0) : 1;
            int ky = py ? (b ? 2 : 0) : 1;
            int kx = px ? (cc ? 2 : 0) : 1;
            int kt = kz * 9 + ky * 3 + kx;
#pragma unroll
            for (int kc = 0; kc < KC; ++kc) {
                const bf16* bp = wb + (long)((kt * KC + kc) * NT) * 512 + lane * 8;
                s8v b0 = *(const s8v*)bp;
                s8v b1 = *(const s8v*)(bp + 512);
#pragma unroll
                for (int mt = 0; mt < 2; ++mt) {
                    int row = ((w + dz) * EY + (2 * mt + vy + dy)) * EX + (vx + dx);
                    s8v av = *(const s8v*)(si + row * PITCH + kc * 32 + q * 8);
                    acc[mt][0] = __builtin_amdgcn_mfma_f32_16x16x32_bf16(
                        av, b0, acc[mt][0], 0, 0, 0);
                    acc[mt][1] = __builtin_amdgcn_mfma_f32_16x16x32_bf16(
                        av, b1, acc[mt][1], 0, 0, 0);
                }
            }
        }
        const int z = 2 * (z0 + w) + pz;
#pragma unroll
        for (int mt = 0; mt < 2; ++mt)
#pragma unroll
            for (int nt = 0; nt < NT; ++nt) {
                const int n_ch = nt * 16 + m;
#pragma unroll
                for (int r = 0; r < 4; ++r) {
                    float v = acc[mt][nt][r];
                    ls[nt] += v; ls2[nt] += v * v;
                }
                if (n_ch < OCR) {
#pragma unroll
                    for (int r = 0; r < 4; ++r) {
                        int vrow = 4 * q + r;
                        int yy = 2 * (y0 + 2 * mt + (vrow >> 3)) + py;
                        int xx = 2 * (x0 + (vrow & 7)) + px;
                        out[(((long)z * OH + yy) * OW + xx) * CSout + n_ch] =
                            __float2bfloat16(acc[mt][nt][r]);
                    }
                }
            }
    }
#pragma unroll
    for (int nt = 0; nt < NT; ++nt) {
        float t = ls[nt], t2 = ls2[nt];
        t  += __shfl_down(t, 32, 64);  t  += __shfl_down(t, 16, 64);
        t2 += __shfl_down(t2, 32, 64); t2 += __shfl_down(t2, 16, 64);
        if (lane < 16) {
            ps[w][2 * (nt * 16 + lane)]     = t;
            ps[w][2 * (nt * 16 + lane) + 1] = t2;
        }
    }
    __syncthreads();
    if (threadIdx.x < 2 * OCR) {
        float v = ps[0][threadIdx.x] + ps[1][threadIdx.x] + ps[2][threadIdx.x]
                + ps[3][threadIdx.x];
        prt[(long)threadIdx.x * nrow + blockIdx.x] = v;
    }
}

// ---------------------------------------------------------------------------
// In-place BN+ReLU on channels-last bf16, NG contiguous 8-channel groups
// (16*NG bytes per row visit) + 2-way spatial ILP. grid: (nblk, C/(8*NG)).
// ---------------------------------------------------------------------------
template <int NG>
__global__ __launch_bounds__(TPB) void bnrelu_cl_k(
    bf16* __restrict__ buf, long spatial, int CS,
    const float* __restrict__ stats, const float* __restrict__ g,
    const float* __restrict__ b, float invN)
{
    const int g0 = blockIdx.y * 8 * NG;
    float sc[8 * NG], sh[8 * NG];
#pragma unroll
    for (int c = 0; c < 8 * NG; ++c) {
        float mean = stats[2 * (g0 + c)] * invN;
        float var  = stats[2 * (g0 + c) + 1] * invN - mean * mean;
        sc[c] = rsqrtf(var + 1e-5f) * g[g0 + c];
        sh[c] = b[g0 + c] - mean * sc[c];
    }
    const long H = spatial >> 1;
    for (long v = (long)blockIdx.x * TPB + threadIdx.x; v < H;
         v += (long)gridDim.x * TPB) {
        bf16* p0 = buf + v * CS + g0;
        bf16* p1 = buf + (v + H) * CS + g0;
        float a0[8 * NG], a1[8 * NG];
#pragma unroll
        for (int k = 0; k < NG; ++k) { ld8(p0 + k * 8, a0 + k * 8); ld8(p1 + k * 8, a1 + k * 8); }
#pragma unroll
        for (int c = 0; c < 8 * NG; ++c) {
            float t0 = a0[c] * sc[c] + sh[c]; a0[c] = t0 > 0.f ? t0 : 0.f;
            float t1 = a1[c] * sc[c] + sh[c]; a1[c] = t1 > 0.f ? t1 : 0.f;
        }
#pragma unroll
        for (int k = 0; k < NG; ++k) { st8(p0 + k * 8, a0 + k * 8); st8(p1 + k * 8, a1 + k * 8); }
    }
}

static inline int nblocks(long n, int per) { return (int)((n + per - 1) / per); }

extern "C" void kernel_launch(void* const* d_in, const int* in_sizes, int n_in,
                              void* d_out, int out_size, void* d_ws, size_t ws_size,
                              hipStream_t stream)
{
    const float* x    = (const float*)d_in[0];
    const float* w0   = (const float*)d_in[1];
    const float* g0   = (const float*)d_in[2];
    const float* b0   = (const float*)d_in[3];
    const float* w1   = (const float*)d_in[4];
    const float* g1   = (const float*)d_in[5];
    const float* b1   = (const float*)d_in[6];
    const float* w2   = (const float*)d_in[7];
    const float* g2   = (const float*)d_in[8];
    const float* b2   = (const float*)d_in[9];
    const float* w3   = (const float*)d_in[10];
    const float* g3   = (const float*)d_in[11];
    const float* b3   = (const float*)d_in[12];
    const float* wt3  = (const float*)d_in[13];
    const float* gt3  = (const float*)d_in[14];
    const float* bt3  = (const float*)d_in[15];
    const float* wt2  = (const float*)d_in[16];
    const float* gt2  = (const float*)d_in[17];
    const float* bt2  = (const float*)d_in[18];
    const float* wt1  = (const float*)d_in[19];
    const float* gt1  = (const float*)d_in[20];
    const float* bt1  = (const float*)d_in[21];
    const float* wout = (const float*)d_in[22];

    const long S128 = 128L * 128 * 128;
    const long S64  = 64L * 64 * 64;
    const long S32  = 32L * 32 * 32;
    const long S16  = 16L * 16 * 16;

    // ---- d_ws: stats | wbo (read by final dispatch -> must NOT be in d_out) | activations
    float* stats = (float*)d_ws;                       // 512 floats
    bf16*  wbo   = (bf16*)((char*)d_ws + 2048);        // 13824 bf16 = 27648 B
    bf16* base = (bf16*)((char*)d_ws + 2048 + 27648);
    bf16* cat1 = base;                 // [128^3][32]: ch0-23 tconv1, ch24-31 s1
    bf16* cat2 = cat1 + S128 * 32;     // [64^3][48] : ch0-31 tconv2, ch32-47 s2
    bf16* cat3 = cat2 + S64 * 48;      // [32^3][64] : ch0-31 tconv3, ch32-63 s4
    bf16* s8   = cat3 + S32 * 64;      // [16^3][64]
    bf16* s1 = cat1 + 24;
    bf16* s2 = cat2 + 32;
    bf16* s4 = cat3 + 32;

    // ---- d_out scratch (all consumed before the final out-conv writes) ----
    bf16*  wbb  = (bf16*)d_out;
    bf16*  wbt1 = wbb;                  // 55296
    bf16*  wbt2 = wbb + 55296;          // 55296
    bf16*  wbt3 = wbb + 110592;         // 55296
    bf16*  wb0  = wbb + 165888;         // 3584
    bf16*  wb1  = wbb + 169472;         // 3584
    bf16*  wb2  = wbb + 173056;         // 14336
    bf16*  wb3  = wbb + 187392;         // 55296 (ends 242688 = 485 KB)
    float* prt  = (float*)d_out + 524288;  // partials, col-major (2 MB offset)

    repack_wb_k <<<nblocks(55296, TPB), TPB, 0, stream>>>(wt1, wbt1, 24, 48, 2, 2);
    repack_wb_k <<<nblocks(55296, TPB), TPB, 0, stream>>>(wt2, wbt2, 32, 64, 2, 2);
    repack_wb_k <<<nblocks(55296, TPB), TPB, 0, stream>>>(wt3, wbt3, 32, 64, 2, 2);
    repack_wbc_k<<<nblocks(3584,  TPB), TPB, 0, stream>>>(w0,  wb0,  8,  8,  7, 1);
    repack_wbc_k<<<nblocks(3584,  TPB), TPB, 0, stream>>>(w1,  wb1,  16, 8,  7, 1);
    repack_wbc_k<<<nblocks(14336, TPB), TPB, 0, stream>>>(w2,  wb2,  32, 16, 14, 2);
    repack_wbc_k<<<nblocks(55296, TPB), TPB, 0, stream>>>(w3,  wb3,  64, 32, 27, 4);
    repack_wbc_k<<<nblocks(13824, TPB), TPB, 0, stream>>>(wout, wbo, 2,  32, 27, 1);

    // ---- encoder ----
    // conv0: fp32 CF [8][128^3] -> s1. tiles 4x8x8 => 8192 blocks.
    conv_mfma_k<8, 8, 1, 4, 8, 8, true, false, true><<<8192, TPB, 0, stream>>>(
        x, wb0, s1, nullptr, 128, 128, 128, 128, 128, 128, 0, 32, prt, 8192);
    sumcol_k<<<16, 64, 0, stream>>>(prt, 8192, stats + 0);
    bnrelu_cl_k<1><<<dim3(2048, 1), TPB, 0, stream>>>(s1, S128, 32, stats + 0, g0, b0, 1.f / S128);

    // conv1: s1 (IC=8) -> s2 (OC=16), stride2. tiles 4x8x8 => 1024 blocks.
    conv_mfma_k<8, 16, 2, 4, 8, 8, false, false, true><<<1024, TPB, 0, stream>>>(
        s1, wb1, s2, nullptr, 128, 128, 128, 64, 64, 64, 32, 48, prt, 1024);
    sumcol_k<<<32, 64, 0, stream>>>(prt, 1024, stats + 16);
    bnrelu_cl_k<2><<<dim3(256, 1), TPB, 0, stream>>>(s2, S64, 48, stats + 16, g1, b1, 1.f / S64);

    // conv2: s2 (IC=16) -> s4 (OC=32), stride2. tiles 4x4x4 => 512 blocks.
    conv_mfma_k<16, 32, 2, 4, 4, 4, false, false, true><<<512, TPB, 0, stream>>>(
        s2, wb2, s4, nullptr, 64, 64, 64, 32, 32, 32, 48, 64, prt, 512);
    sumcol_k<<<64, 64, 0, stream>>>(prt, 512, stats + 48);
    bnrelu_cl_k<4><<<dim3(32, 1), TPB, 0, stream>>>(s4, S32, 64, stats + 48, g2, b2, 1.f / S32);

    // conv3: s4 (IC=32) -> s8 (OC=64), stride2. tiles 4x4x4 => 64 blocks.
    conv_mfma_k<32, 64, 2, 4, 4, 4, false, false, true><<<64, TPB, 0, stream>>>(
        s4, wb3, s8, nullptr, 32, 32, 32, 16, 16, 16, 64, 64, prt, 64);
    sumcol_k<<<128, 64, 0, stream>>>(prt, 64, stats + 112);
    bnrelu_cl_k<4><<<dim3(4, 2), TPB, 0, stream>>>(s8, S16, 64, stats + 112, g3, b3, 1.f / S16);

    // ---- decoder ----
    // tconv3: s8 (IC=64) -> cat3 ch0-31 (OC=32), 16->32. 32 blocks.
    tconv_mfma_k<64, 32><<<32, TPB, 0, stream>>>(
        s8, wbt3, cat3, 16, 16, 16, 64, 64, prt, 32);
    sumcol_k<<<64, 64, 0, stream>>>(prt, 32, stats + 240);
    bnrelu_cl_k<4><<<dim3(32, 1), TPB, 0, stream>>>(cat3, S32, 64, stats + 240, gt3, bt3, 1.f / S32);

    // tconv2: cat3 (IC=64) -> cat2 ch0-31 (OC=32), 32->64. 256 blocks.
    tconv_mfma_k<64, 32><<<256, TPB, 0, stream>>>(
        cat3, wbt2, cat2, 32, 32, 32, 64, 48, prt, 256);
    sumcol_k<<<64, 64, 0, stream>>>(prt, 256, stats + 304);
    bnrelu_cl_k<4><<<dim3(256, 1), TPB, 0, stream>>>(cat2, S64, 48, stats + 304, gt2, bt2, 1.f / S64);

    // tconv1: cat2 (IC=48) -> cat1 ch0-23 (OC=24), 64->128. 2048 blocks.
    tconv_mfma_k<48, 24><<<2048, TPB, 0, stream>>>(
        cat2, wbt1, cat1, 64, 64, 64, 48, 32, prt, 2048);
    sumcol_k<<<48, 64, 0, stream>>>(prt, 2048, stats + 368);
    bnrelu_cl_k<3><<<dim3(2048, 1), TPB, 0, stream>>>(cat1, S128, 32, stats + 368, gt1, bt1, 1.f / S128);

    // out conv: cat1 (IC=32) -> d_out fp32 [2][128^3]. tiles 4x8x8 => 8192.
    conv_mfma_k<32, 2, 1, 4, 8, 8, false, true, false><<<8192, TPB, 0, stream>>>(
        cat1, wbo, nullptr, (float*)d_out, 128, 128, 128, 128, 128, 128, 32, 0,
        nullptr, 0);
}